// Round 2
// baseline (1611.384 us; speedup 1.0000x reference)
//
#include <hip/hip_runtime.h>
#include <hip/hip_bf16.h>

// FrequencyAwareSumAttention — round 2: fp32 q/k/v storage (kill bf16 quantization
// on the DFT path and the V path). B=4 T=256 J=17 C=512 H=8 d=64; HEADS=544.
// K1 qkv GEMM (fp32) -> q,k,v fp32 head-major [head][t][d]
// K2 per-head truncated DFT (64 bins, fp32 in) + freq softmax -> af [head][64][64]
// K3 time softmax (bf16 QK^T) + bilinear interp + combine + PV (fp32 V) -> out_perm
// K4 proj GEMM + bias -> d_out

#define SCALE 0.125f

__device__ __forceinline__ float bf2f(unsigned short u) {
  return __uint_as_float(((unsigned int)u) << 16);
}
__device__ __forceinline__ unsigned short f2bf(float f) {
  unsigned int u = __float_as_uint(f);
  u += 0x7FFFu + ((u >> 16) & 1u);
  return (unsigned short)(u >> 16);
}

// ---------------- K1: qkv = x @ w_qkv, scatter fp32 head-major ----------------
__global__ __launch_bounds__(256) void qkv_gemm(
    const float* __restrict__ x, const float* __restrict__ w,
    float* __restrict__ q, float* __restrict__ k, float* __restrict__ v) {
  __shared__ float As[16][64];  // [kk][m] transposed
  __shared__ float Bs[16][64];  // [kk][n]
  const int tid = threadIdx.x;
  const int bm = blockIdx.x, bn = blockIdx.y;
  const int ty = tid >> 4, tx = tid & 15;
  const int arow = tid >> 2, akq = tid & 3;
  const int bkk = tid >> 4, bnq = tid & 15;
  const float* xrow = x + (bm * 64 + arow) * 512 + akq * 4;
  const float* wcol = w + bn * 64 + bnq * 4;
  float acc[4][4];
#pragma unroll
  for (int i = 0; i < 4; ++i)
#pragma unroll
    for (int jj = 0; jj < 4; ++jj) acc[i][jj] = 0.f;

  for (int k0 = 0; k0 < 512; k0 += 16) {
    float4 a4 = *(const float4*)(xrow + k0);
    float4 b4 = *(const float4*)(wcol + (size_t)(k0 + bkk) * 1536);
    As[akq * 4 + 0][arow] = a4.x;
    As[akq * 4 + 1][arow] = a4.y;
    As[akq * 4 + 2][arow] = a4.z;
    As[akq * 4 + 3][arow] = a4.w;
    *(float4*)&Bs[bkk][bnq * 4] = b4;
    __syncthreads();
#pragma unroll
    for (int kk = 0; kk < 16; ++kk) {
      float4 av = *(const float4*)&As[kk][ty * 4];
      float4 bv = *(const float4*)&Bs[kk][tx * 4];
      float a[4] = {av.x, av.y, av.z, av.w};
      float bb[4] = {bv.x, bv.y, bv.z, bv.w};
#pragma unroll
      for (int i = 0; i < 4; ++i)
#pragma unroll
        for (int jj = 0; jj < 4; ++jj) acc[i][jj] += a[i] * bb[jj];
    }
    __syncthreads();
  }
  // epilogue: c = qi*512 + h*64 + dd ; row r = (b*256+t)*17 + j
  const int cbase = bn * 64 + tx * 4;
  const int qi = cbase >> 9;
  const int h = (cbase >> 6) & 7;
  const int ddb = cbase & 63;
  float* dst = (qi == 0) ? q : (qi == 1) ? k : v;
#pragma unroll
  for (int i = 0; i < 4; ++i) {
    int r = bm * 64 + ty * 4 + i;
    int j = r % 17;
    int bt = r / 17;
    int t = bt & 255;
    int b = bt >> 8;
    int base = ((b * 8 + h) * 17 + j) * 16384 + t * 64 + ddb;
    *(float4*)&dst[base] = make_float4(acc[i][0], acc[i][1], acc[i][2], acc[i][3]);
  }
}

// ---------------- K2: per-head 64-bin DFT over T + freq softmax ----------------
__global__ __launch_bounds__(256) void freq_kernel(
    const float* __restrict__ qg, const float* __restrict__ kg,
    float* __restrict__ af_out) {
  __shared__ float qfr[64][65], qfi[64][65];    // [f][d]
  __shared__ float kfrt[64][65], kfit[64][65];  // [d][g] (transposed)
  __shared__ float cosT[256], sinT[256];
  const int tid = threadIdx.x;
  const int head = blockIdx.x;

  {
    float ang = (float)tid * (6.283185307179586f / 256.0f);
    float s, c;
    __sincosf(ang, &s, &c);
    cosT[tid] = c;
    sinT[tid] = s;
  }
  __syncthreads();

  const int dd = tid & 63;
  const int f0 = (tid >> 6) << 4;  // this wave handles freqs f0..f0+15
  const float* qp = qg + head * 16384 + dd;
  const float* kp = kg + head * 16384 + dd;

  // DFT of q: qf[f][dd] = sum_t q[t][dd] * e(f*t),  e = (cos, sin) of 2*pi*idx/256
  {
    float fr[16], fi[16];
#pragma unroll
    for (int i = 0; i < 16; ++i) { fr[i] = 0.f; fi[i] = 0.f; }
    for (int t = 0; t < 256; ++t) {
      float a = qp[t * 64];
      int idx = (f0 * t) & 255;
      const int step = t;
#pragma unroll
      for (int i = 0; i < 16; ++i) {
        fr[i] += cosT[idx] * a;
        fi[i] += sinT[idx] * a;
        idx = (idx + step) & 255;
      }
    }
#pragma unroll
    for (int i = 0; i < 16; ++i) {
      qfr[f0 + i][dd] = fr[i];
      qfi[f0 + i][dd] = fi[i];
    }
  }
  // DFT of k -> transposed stores
  {
    float fr[16], fi[16];
#pragma unroll
    for (int i = 0; i < 16; ++i) { fr[i] = 0.f; fi[i] = 0.f; }
    for (int t = 0; t < 256; ++t) {
      float a = kp[t * 64];
      int idx = (f0 * t) & 255;
      const int step = t;
#pragma unroll
      for (int i = 0; i < 16; ++i) {
        fr[i] += cosT[idx] * a;
        fi[i] += sinT[idx] * a;
        idx = (idx + step) & 255;
      }
    }
#pragma unroll
    for (int i = 0; i < 16; ++i) {
      kfrt[dd][f0 + i] = fr[i];
      kfit[dd][f0 + i] = fi[i];
    }
  }
  __syncthreads();

  // af_real[f][g] = scale * sum_d (qfr*kfr + qfi*kfi); softmax over g (g = lane)
  {
    const int g = tid & 63;
    float av[16];
#pragma unroll
    for (int i = 0; i < 16; ++i) {
      const int f = f0 + i;
      float a0 = 0.f, a1 = 0.f;
#pragma unroll 8
      for (int d = 0; d < 64; ++d) {
        a0 += qfr[f][d] * kfrt[d][g];
        a1 += qfi[f][d] * kfit[d][g];
      }
      av[i] = (a0 + a1) * SCALE;
    }
    float* outp = af_out + head * 4096;
#pragma unroll
    for (int i = 0; i < 16; ++i) {
      float m = av[i];
#pragma unroll
      for (int off = 32; off >= 1; off >>= 1) m = fmaxf(m, __shfl_xor(m, off));
      float e = __expf(av[i] - m);
      float s = e;
#pragma unroll
      for (int off = 32; off >= 1; off >>= 1) s += __shfl_xor(s, off);
      outp[(f0 + i) * 64 + g] = e / s;
    }
  }
}

// ---------------- K3: time softmax + resize-interp + combine + PV ----------------
__global__ __launch_bounds__(256) void attn_kernel(
    const float* __restrict__ qg, const float* __restrict__ kg,
    const float* __restrict__ vg, const float* __restrict__ af,
    const float* __restrict__ att_map, const float* __restrict__ weight,
    const float* __restrict__ fgate, float* __restrict__ out_perm) {
  __shared__ unsigned short Ks[256][64];
  __shared__ unsigned short Qs[64][68];
  __shared__ float afl[64][65];
  __shared__ float S[64][257];
  const int tid = threadIdx.x;
  const int t0 = blockIdx.x << 6;  // row tile (4 tiles of 64)
  const int head = blockIdx.y;
  const int j = head % 17;
  const int hb = head / 17;
  const int h = hb & 7;
  const int b = hb >> 3;

  // stage K (fp32 -> bf16) and Q tile (fp32 -> bf16)
  const float4* ksrc = (const float4*)(kg + head * 16384);
  for (int i = tid; i < 4096; i += 256) {
    float4 f4 = ksrc[i];
    int s = i >> 4, dq = (i & 15) << 2;
    Ks[s][dq + 0] = f2bf(f4.x);
    Ks[s][dq + 1] = f2bf(f4.y);
    Ks[s][dq + 2] = f2bf(f4.z);
    Ks[s][dq + 3] = f2bf(f4.w);
  }
  const float4* qsrc = (const float4*)(qg + head * 16384 + t0 * 64);
  for (int i = tid; i < 1024; i += 256) {
    float4 f4 = qsrc[i];
    int t = i >> 4, dq = (i & 15) << 2;
    Qs[t][dq + 0] = f2bf(f4.x);
    Qs[t][dq + 1] = f2bf(f4.y);
    Qs[t][dq + 2] = f2bf(f4.z);
    Qs[t][dq + 3] = f2bf(f4.w);
  }
  const float4* asrc = (const float4*)(af + head * 4096);
  for (int i = tid; i < 1024; i += 256) {
    float4 a4 = asrc[i];
    int f = i >> 4, gq = (i & 15) << 2;
    afl[f][gq + 0] = a4.x;
    afl[f][gq + 1] = a4.y;
    afl[f][gq + 2] = a4.z;
    afl[f][gq + 3] = a4.w;
  }
  __syncthreads();

  // S[t][s] = scale * q[t] . k[s]   (t = lane, s-range per wave)
  {
    const int t = tid & 63;
    const int sq = tid >> 6;
    float qr[64];
#pragma unroll
    for (int d = 0; d < 64; d += 4) {
      ushort4 u = *(const ushort4*)&Qs[t][d];
      qr[d + 0] = bf2f(u.x);
      qr[d + 1] = bf2f(u.y);
      qr[d + 2] = bf2f(u.z);
      qr[d + 3] = bf2f(u.w);
    }
    for (int s = 0; s < 64; ++s) {
      const int sg = (sq << 6) + s;
      float a0 = 0.f, a1 = 0.f, a2 = 0.f, a3 = 0.f;
#pragma unroll
      for (int d = 0; d < 64; d += 4) {
        ushort4 u = *(const ushort4*)&Ks[sg][d];
        a0 += qr[d + 0] * bf2f(u.x);
        a1 += qr[d + 1] * bf2f(u.y);
        a2 += qr[d + 2] * bf2f(u.z);
        a3 += qr[d + 3] * bf2f(u.w);
      }
      S[t][sg] = (a0 + a1 + a2 + a3) * SCALE;
    }
  }
  __syncthreads();

  // per-row softmax + bilinear-resize freq interp + combine; overwrite S with attn
  {
    const float wv = weight[0];
    const float gate = 1.0f / (1.0f + __expf(-fgate[0]));
    const int lane = tid & 63;
    const int wid = tid >> 6;
    const float* amh = att_map + (size_t)head * 65536;
    for (int tt = wid * 16; tt < wid * 16 + 16; ++tt) {
      const int tglob = t0 + tt;
      float srcf = fmaxf((tglob + 0.5f) * (129.0f / 256.0f) - 0.5f, 0.0f);
      int f0r = (int)srcf;  // floor (srcf >= 0)
      float wf = srcf - (float)f0r;
      int f1r = f0r + 1;
      if (f1r > 128) f1r = 128;
      const bool v0 = (f0r < 64), v1 = (f1r < 64);

      float s4[4], e4[4];
#pragma unroll
      for (int c = 0; c < 4; ++c) s4[c] = S[tt][lane + (c << 6)];
      float m = fmaxf(fmaxf(s4[0], s4[1]), fmaxf(s4[2], s4[3]));
#pragma unroll
      for (int off = 32; off >= 1; off >>= 1) m = fmaxf(m, __shfl_xor(m, off));
      float rs = 0.f;
#pragma unroll
      for (int c = 0; c < 4; ++c) {
        e4[c] = __expf(s4[c] - m);
        rs += e4[c];
      }
#pragma unroll
      for (int off = 32; off >= 1; off >>= 1) rs += __shfl_xor(rs, off);
      const float inv = 1.0f / rs;

#pragma unroll
      for (int c = 0; c < 4; ++c) {
        const int s = lane + (c << 6);
        float srcg = fmaxf((s + 0.5f) * 0.25f - 0.5f, 0.0f);
        int g0 = (int)srcg;
        float wc = srcg - (float)g0;
        int g1 = g0 + 1;
        if (g1 > 63) g1 = 63;
        float fr = 0.f;
        if (v0) fr += (1.0f - wf) * (afl[f0r][g0] * (1.0f - wc) + afl[f0r][g1] * wc);
        if (v1) fr += wf * (afl[f1r][g0] * (1.0f - wc) + afl[f1r][g1] * wc);
        const float pt = e4[c] * inv;
        const float am = amh[tglob * 256 + s];
        S[tt][s] = wv * (gate * fr + (1.0f - gate) * pt) + (1.0f - wv) * am;
      }
    }
  }
  __syncthreads();

  // PV: out[t][dd] = sum_s attn[t][s] * V[s][dd]  (V fp32 from global, L1-resident)
  {
    const int ddq = tid & 15;
    const int tq = tid >> 4;
    const float* vcol = vg + head * 16384 + (ddq << 2);
    float acc[4][4];
#pragma unroll
    for (int i = 0; i < 4; ++i)
#pragma unroll
      for (int jj = 0; jj < 4; ++jj) acc[i][jj] = 0.f;
#pragma unroll 4
    for (int s = 0; s < 256; ++s) {
      float4 vv = *(const float4*)(vcol + s * 64);
#pragma unroll
      for (int i = 0; i < 4; ++i) {
        const float p = S[tq * 4 + i][s];
        acc[i][0] += p * vv.x;
        acc[i][1] += p * vv.y;
        acc[i][2] += p * vv.z;
        acc[i][3] += p * vv.w;
      }
    }
#pragma unroll
    for (int i = 0; i < 4; ++i) {
      const int tglob = t0 + tq * 4 + i;
      float4 o = make_float4(acc[i][0], acc[i][1], acc[i][2], acc[i][3]);
      *(float4*)&out_perm[(size_t)(((b * 256 + tglob) * 17 + j) << 9) + (h << 6) + (ddq << 2)] = o;
    }
  }
}

// ---------------- K4: d_out = out_perm @ w_proj + b_proj ----------------
__global__ __launch_bounds__(256) void proj_gemm(
    const float* __restrict__ A, const float* __restrict__ w,
    const float* __restrict__ bias, float* __restrict__ out) {
  __shared__ float As[16][64];
  __shared__ float Bs[16][64];
  const int tid = threadIdx.x;
  const int bm = blockIdx.x, bn = blockIdx.y;
  const int ty = tid >> 4, tx = tid & 15;
  const int arow = tid >> 2, akq = tid & 3;
  const int bkk = tid >> 4, bnq = tid & 15;
  const float* arp = A + (bm * 64 + arow) * 512 + akq * 4;
  const float* wcol = w + bn * 64 + bnq * 4;
  float acc[4][4];
#pragma unroll
  for (int i = 0; i < 4; ++i)
#pragma unroll
    for (int jj = 0; jj < 4; ++jj) acc[i][jj] = 0.f;

  for (int k0 = 0; k0 < 512; k0 += 16) {
    float4 a4 = *(const float4*)(arp + k0);
    float4 b4 = *(const float4*)(wcol + (size_t)(k0 + bkk) * 512);
    As[akq * 4 + 0][arow] = a4.x;
    As[akq * 4 + 1][arow] = a4.y;
    As[akq * 4 + 2][arow] = a4.z;
    As[akq * 4 + 3][arow] = a4.w;
    *(float4*)&Bs[bkk][bnq * 4] = b4;
    __syncthreads();
#pragma unroll
    for (int kk = 0; kk < 16; ++kk) {
      float4 av = *(const float4*)&As[kk][ty * 4];
      float4 bv = *(const float4*)&Bs[kk][tx * 4];
      float a[4] = {av.x, av.y, av.z, av.w};
      float bb[4] = {bv.x, bv.y, bv.z, bv.w};
#pragma unroll
      for (int i = 0; i < 4; ++i)
#pragma unroll
        for (int jj = 0; jj < 4; ++jj) acc[i][jj] += a[i] * bb[jj];
    }
    __syncthreads();
  }
  const int cbase = bn * 64 + tx * 4;
  float4 bi = *(const float4*)&bias[cbase];
#pragma unroll
  for (int i = 0; i < 4; ++i) {
    const int r = bm * 64 + ty * 4 + i;
    float4 o = make_float4(acc[i][0] + bi.x, acc[i][1] + bi.y, acc[i][2] + bi.z,
                           acc[i][3] + bi.w);
    *(float4*)&out[(size_t)r * 512 + cbase] = o;
  }
}

extern "C" void kernel_launch(void* const* d_in, const int* in_sizes, int n_in,
                              void* d_out, int out_size, void* d_ws, size_t ws_size,
                              hipStream_t stream) {
  (void)in_sizes; (void)n_in; (void)out_size; (void)ws_size;
  const float* x = (const float*)d_in[0];
  const float* att_map = (const float*)d_in[1];
  const float* weight = (const float*)d_in[2];
  const float* w_qkv = (const float*)d_in[3];
  const float* w_proj = (const float*)d_in[4];
  const float* b_proj = (const float*)d_in[5];
  const float* fgate = (const float*)d_in[6];
  float* out = (float*)d_out;

  char* ws = (char*)d_ws;
  const size_t HB = 35651584;  // 544*16384 f32 bytes
  float* qb = (float*)(ws);
  float* kb = (float*)(ws + HB);
  float* vb = (float*)(ws + 2 * HB);
  float* af = (float*)(ws + 3 * HB);                  // 544*4096 f32 = 8,912,896 B
  float* out_perm = (float*)(ws + 3 * HB + 8912896);  // (B,T,J,C) f32 = 35,651,584 B

  qkv_gemm<<<dim3(272, 24), 256, 0, stream>>>(x, w_qkv, qb, kb, vb);
  freq_kernel<<<544, 256, 0, stream>>>(qb, kb, af);
  attn_kernel<<<dim3(4, 544), 256, 0, stream>>>(qb, kb, vb, af, att_map, weight,
                                                fgate, out_perm);
  proj_gemm<<<dim3(272, 8), 256, 0, stream>>>(out_perm, w_proj, b_proj, out);
}

// Round 3
// 1070.544 us; speedup vs baseline: 1.5052x; 1.5052x over previous
//
#include <hip/hip_runtime.h>
#include <hip/hip_bf16.h>

// FrequencyAwareSumAttention — round 3: MFMA attention kernel (K3).
// K1 qkv GEMM (fp32) -> q,k,v fp32 head-major [head][t][d]   (unchanged)
// K2 per-head truncated DFT + freq softmax -> af [head][64][64] (unchanged)
// K3 MFMA bf16 QK^T + in-reg softmax/interp/combine + MFMA bf16 PV
// K4 proj GEMM + bias -> d_out                                (unchanged)

#define SCALE 0.125f

typedef __attribute__((ext_vector_type(4))) float f32x4;
typedef __attribute__((ext_vector_type(8))) short bf16x8;

__device__ __forceinline__ float bf2f(unsigned short u) {
  return __uint_as_float(((unsigned int)u) << 16);
}
__device__ __forceinline__ unsigned short f2bf(float f) {
  unsigned int u = __float_as_uint(f);
  u += 0x7FFFu + ((u >> 16) & 1u);
  return (unsigned short)(u >> 16);
}

// ---------------- K1: qkv = x @ w_qkv, scatter fp32 head-major ----------------
__global__ __launch_bounds__(256) void qkv_gemm(
    const float* __restrict__ x, const float* __restrict__ w,
    float* __restrict__ q, float* __restrict__ k, float* __restrict__ v) {
  __shared__ float As[16][64];
  __shared__ float Bs[16][64];
  const int tid = threadIdx.x;
  const int bm = blockIdx.x, bn = blockIdx.y;
  const int ty = tid >> 4, tx = tid & 15;
  const int arow = tid >> 2, akq = tid & 3;
  const int bkk = tid >> 4, bnq = tid & 15;
  const float* xrow = x + (bm * 64 + arow) * 512 + akq * 4;
  const float* wcol = w + bn * 64 + bnq * 4;
  float acc[4][4];
#pragma unroll
  for (int i = 0; i < 4; ++i)
#pragma unroll
    for (int jj = 0; jj < 4; ++jj) acc[i][jj] = 0.f;

  for (int k0 = 0; k0 < 512; k0 += 16) {
    float4 a4 = *(const float4*)(xrow + k0);
    float4 b4 = *(const float4*)(wcol + (size_t)(k0 + bkk) * 1536);
    As[akq * 4 + 0][arow] = a4.x;
    As[akq * 4 + 1][arow] = a4.y;
    As[akq * 4 + 2][arow] = a4.z;
    As[akq * 4 + 3][arow] = a4.w;
    *(float4*)&Bs[bkk][bnq * 4] = b4;
    __syncthreads();
#pragma unroll
    for (int kk = 0; kk < 16; ++kk) {
      float4 av = *(const float4*)&As[kk][ty * 4];
      float4 bv = *(const float4*)&Bs[kk][tx * 4];
      float a[4] = {av.x, av.y, av.z, av.w};
      float bb[4] = {bv.x, bv.y, bv.z, bv.w};
#pragma unroll
      for (int i = 0; i < 4; ++i)
#pragma unroll
        for (int jj = 0; jj < 4; ++jj) acc[i][jj] += a[i] * bb[jj];
    }
    __syncthreads();
  }
  const int cbase = bn * 64 + tx * 4;
  const int qi = cbase >> 9;
  const int h = (cbase >> 6) & 7;
  const int ddb = cbase & 63;
  float* dst = (qi == 0) ? q : (qi == 1) ? k : v;
#pragma unroll
  for (int i = 0; i < 4; ++i) {
    int r = bm * 64 + ty * 4 + i;
    int j = r % 17;
    int bt = r / 17;
    int t = bt & 255;
    int b = bt >> 8;
    int base = ((b * 8 + h) * 17 + j) * 16384 + t * 64 + ddb;
    *(float4*)&dst[base] = make_float4(acc[i][0], acc[i][1], acc[i][2], acc[i][3]);
  }
}

// ---------------- K2: per-head 64-bin DFT over T + freq softmax ----------------
__global__ __launch_bounds__(256) void freq_kernel(
    const float* __restrict__ qg, const float* __restrict__ kg,
    float* __restrict__ af_out) {
  __shared__ float qfr[64][65], qfi[64][65];
  __shared__ float kfrt[64][65], kfit[64][65];
  __shared__ float cosT[256], sinT[256];
  const int tid = threadIdx.x;
  const int head = blockIdx.x;

  {
    float ang = (float)tid * (6.283185307179586f / 256.0f);
    float s, c;
    __sincosf(ang, &s, &c);
    cosT[tid] = c;
    sinT[tid] = s;
  }
  __syncthreads();

  const int dd = tid & 63;
  const int f0 = (tid >> 6) << 4;
  const float* qp = qg + head * 16384 + dd;
  const float* kp = kg + head * 16384 + dd;

  {
    float fr[16], fi[16];
#pragma unroll
    for (int i = 0; i < 16; ++i) { fr[i] = 0.f; fi[i] = 0.f; }
    for (int t = 0; t < 256; ++t) {
      float a = qp[t * 64];
      int idx = (f0 * t) & 255;
      const int step = t;
#pragma unroll
      for (int i = 0; i < 16; ++i) {
        fr[i] += cosT[idx] * a;
        fi[i] += sinT[idx] * a;
        idx = (idx + step) & 255;
      }
    }
#pragma unroll
    for (int i = 0; i < 16; ++i) {
      qfr[f0 + i][dd] = fr[i];
      qfi[f0 + i][dd] = fi[i];
    }
  }
  {
    float fr[16], fi[16];
#pragma unroll
    for (int i = 0; i < 16; ++i) { fr[i] = 0.f; fi[i] = 0.f; }
    for (int t = 0; t < 256; ++t) {
      float a = kp[t * 64];
      int idx = (f0 * t) & 255;
      const int step = t;
#pragma unroll
      for (int i = 0; i < 16; ++i) {
        fr[i] += cosT[idx] * a;
        fi[i] += sinT[idx] * a;
        idx = (idx + step) & 255;
      }
    }
#pragma unroll
    for (int i = 0; i < 16; ++i) {
      kfrt[dd][f0 + i] = fr[i];
      kfit[dd][f0 + i] = fi[i];
    }
  }
  __syncthreads();

  {
    const int g = tid & 63;
    float av[16];
#pragma unroll
    for (int i = 0; i < 16; ++i) {
      const int f = f0 + i;
      float a0 = 0.f, a1 = 0.f;
#pragma unroll 8
      for (int d = 0; d < 64; ++d) {
        a0 += qfr[f][d] * kfrt[d][g];
        a1 += qfi[f][d] * kfit[d][g];
      }
      av[i] = (a0 + a1) * SCALE;
    }
    float* outp = af_out + head * 4096;
#pragma unroll
    for (int i = 0; i < 16; ++i) {
      float m = av[i];
#pragma unroll
      for (int off = 32; off >= 1; off >>= 1) m = fmaxf(m, __shfl_xor(m, off));
      float e = __expf(av[i] - m);
      float s = e;
#pragma unroll
      for (int off = 32; off >= 1; off >>= 1) s += __shfl_xor(s, off);
      outp[(f0 + i) * 64 + g] = e / s;
    }
  }
}

// ---------------- K3: MFMA attention ----------------
// block = 256 thr (4 waves); blockIdx.x = t-tile (64 rows), blockIdx.y = head.
// wave w owns rows [t0 + w*16, +16). MFMA 16x16x32 bf16.
// Layouts (guide §3, m89/m91): A: m=lane&15, k=(lane>>4)*8+i
//                              B: k=(lane>>4)*8+i, n=lane&15
//                              D: col=lane&15, row=(lane>>4)*4+reg
__global__ __launch_bounds__(256) void attn_kernel(
    const float* __restrict__ qg, const float* __restrict__ kg,
    const float* __restrict__ vg, const float* __restrict__ af,
    const float* __restrict__ att_map, const float* __restrict__ weight,
    const float* __restrict__ fgate, float* __restrict__ out_perm) {
  // K bf16, row-major [s][d], XOR-swizzled: byte = s*128 + ((d*2) ^ ((s&7)<<4))
  __shared__ unsigned short Ks[256 * 64];
  // V bf16, TRANSPOSED [d][s], swizzled: byte = d*512 + ((s*2) ^ ((d&7)<<4))
  __shared__ unsigned short Vt[64 * 256];
  // af bf16 [64][66]
  __shared__ unsigned short afl[64 * 66];
  // per-wave P scratch [16 rows][40 cols] bf16 (20-dword stride: conflict-free)
  __shared__ unsigned short Psc[4][16 * 40];

  const int tid = threadIdx.x;
  const int t0 = blockIdx.x << 6;
  const int head = blockIdx.y;
  const int jj = head % 17;
  const int hb = head / 17;
  const int h = hb & 7;
  const int b = hb >> 3;

  // ---- stage K (swizzled bf16) and Vt (transposed swizzled bf16) ----
  const float4* ksrc = (const float4*)(kg + head * 16384);
  const float4* vsrc = (const float4*)(vg + head * 16384);
  for (int i = tid; i < 4096; i += 256) {
    int s = i >> 4, dq = i & 15;  // d0 = dq*4
    float4 kf = ksrc[i];
    ushort4 k4 = make_ushort4(f2bf(kf.x), f2bf(kf.y), f2bf(kf.z), f2bf(kf.w));
    int koff = s * 128 + ((dq * 8) ^ ((s & 7) << 4));
    *(ushort4*)((char*)Ks + koff) = k4;
    float4 vf = vsrc[i];
    float vv[4] = {vf.x, vf.y, vf.z, vf.w};
#pragma unroll
    for (int c = 0; c < 4; ++c) {
      int d = dq * 4 + c;
      int voff = d * 512 + ((s * 2) ^ ((d & 7) << 4));
      *(unsigned short*)((char*)Vt + voff) = f2bf(vv[c]);
    }
  }
  const float4* asrc = (const float4*)(af + head * 4096);
  for (int i = tid; i < 1024; i += 256) {
    float4 a4 = asrc[i];
    int f = i >> 4, gq = (i & 15) << 2;
    ushort4 a4b = make_ushort4(f2bf(a4.x), f2bf(a4.y), f2bf(a4.z), f2bf(a4.w));
    *(ushort4*)&afl[f * 66 + gq] = a4b;
  }
  __syncthreads();

  const int w = tid >> 6, lane = tid & 63;
  const int lr = lane & 15, lg = lane >> 4;
  const int tw = t0 + w * 16;

  // ---- Q A-fragments straight from global (fp32 -> bf16) ----
  bf16x8 aq[2];
  {
    const float* qrow = qg + head * 16384 + (tw + lr) * 64 + lg * 8;
#pragma unroll
    for (int kc = 0; kc < 2; ++kc) {
      float4 q0 = *(const float4*)(qrow + kc * 32);
      float4 q1 = *(const float4*)(qrow + kc * 32 + 4);
      bf16x8 a;
      a[0] = (short)f2bf(q0.x); a[1] = (short)f2bf(q0.y);
      a[2] = (short)f2bf(q0.z); a[3] = (short)f2bf(q0.w);
      a[4] = (short)f2bf(q1.x); a[5] = (short)f2bf(q1.y);
      a[6] = (short)f2bf(q1.z); a[7] = (short)f2bf(q1.w);
      aq[kc] = a;
    }
  }

  // ---- QK^T: S[t 16][s 256] -> per-lane f32x4 S[16 ntiles] ----
  f32x4 S[16];
#pragma unroll
  for (int nt = 0; nt < 16; ++nt) {
    f32x4 accv = {0.f, 0.f, 0.f, 0.f};
#pragma unroll
    for (int kc = 0; kc < 2; ++kc) {
      int srow = nt * 16 + lr;
      int d0 = kc * 32 + lg * 8;
      int off = srow * 128 + ((d0 * 2) ^ ((srow & 7) << 4));
      bf16x8 bk = *(bf16x8*)((char*)Ks + off);
      accv = __builtin_amdgcn_mfma_f32_16x16x32_bf16(aq[kc], bk, accv, 0, 0, 0);
    }
    S[nt] = accv;
  }

  // ---- softmax over s (rows t = tw + lg*4 + j), 16-lane xor groups ----
  float inv[4], mrow[4];
#pragma unroll
  for (int j = 0; j < 4; ++j) {
    float m = -1e30f;
#pragma unroll
    for (int nt = 0; nt < 16; ++nt) m = fmaxf(m, S[nt][j]);
#pragma unroll
    for (int mask = 1; mask < 16; mask <<= 1) m = fmaxf(m, __shfl_xor(m, mask));
    mrow[j] = m;
  }
#pragma unroll
  for (int j = 0; j < 4; ++j) {
    float rs = 0.f;
#pragma unroll
    for (int nt = 0; nt < 16; ++nt) {
      float e = __expf((S[nt][j] - mrow[j]) * SCALE);
      S[nt][j] = e;
      rs += e;
    }
#pragma unroll
    for (int mask = 1; mask < 16; mask <<= 1) rs += __shfl_xor(rs, mask);
    inv[j] = 1.0f / rs;
  }

  // ---- combine: interp(freq) + att_map + time softmax -> P (overwrite S) ----
  {
    const float wv = weight[0];
    const float gate = 1.0f / (1.0f + __expf(-fgate[0]));
    const float* amh = att_map + (size_t)head * 65536;
#pragma unroll
    for (int j = 0; j < 4; ++j) {
      const int t = tw + lg * 4 + j;
      float srcf = fmaxf((t + 0.5f) * (129.0f / 256.0f) - 0.5f, 0.0f);
      int f0r = (int)srcf;
      float wf = srcf - (float)f0r;
      int f1r = f0r + 1;
      if (f1r > 128) f1r = 128;
      const bool v0 = (f0r < 64), v1 = (f1r < 64);
#pragma unroll
      for (int nt = 0; nt < 16; ++nt) {
        const int s = nt * 16 + lr;
        float am = amh[t * 256 + s];
        float srcg = fmaxf((s + 0.5f) * 0.25f - 0.5f, 0.0f);
        int g0 = (int)srcg;
        float wc = srcg - (float)g0;
        int g1 = g0 + 1;
        if (g1 > 63) g1 = 63;
        float fr = 0.f;
        if (v0)
          fr += (1.0f - wf) *
                (bf2f(afl[f0r * 66 + g0]) * (1.0f - wc) + bf2f(afl[f0r * 66 + g1]) * wc);
        if (v1)
          fr += wf *
                (bf2f(afl[f1r * 66 + g0]) * (1.0f - wc) + bf2f(afl[f1r * 66 + g1]) * wc);
        float pt = S[nt][j] * inv[j];
        S[nt][j] = wv * (gate * fr + (1.0f - gate) * pt) + (1.0f - wv) * am;
      }
    }
  }

  // ---- PV: out[t 16][d 64] += P[t][s] V[s][d], s-blocks of 32 ----
  f32x4 O[4];
#pragma unroll
  for (int dt = 0; dt < 4; ++dt) O[dt] = (f32x4){0.f, 0.f, 0.f, 0.f};
  unsigned short* psc = Psc[w];
#pragma unroll
  for (int sb = 0; sb < 8; ++sb) {
    // write P tile [16 t][32 s-local] bf16; row=lg*4+j, col=half*16+lr
#pragma unroll
    for (int half = 0; half < 2; ++half) {
      const int nt = sb * 2 + half;
#pragma unroll
      for (int j = 0; j < 4; ++j) {
        psc[(lg * 4 + j) * 40 + half * 16 + lr] = f2bf(S[nt][j]);
      }
    }
    // A-frag: P[m=lr][k=lg*8+i]  (16B aligned: 40 el = 80 B rows)
    bf16x8 pa = *(bf16x8*)&psc[lr * 40 + lg * 8];
    // B-frags from Vt: B[k=s][n=d], d = dt*16+lr, s = sb*32 + lg*8 + i
#pragma unroll
    for (int dt = 0; dt < 4; ++dt) {
      int d = dt * 16 + lr;
      int s0 = sb * 32 + lg * 8;
      int off = d * 512 + ((s0 * 2) ^ ((d & 7) << 4));
      bf16x8 bv = *(bf16x8*)((char*)Vt + off);
      O[dt] = __builtin_amdgcn_mfma_f32_16x16x32_bf16(pa, bv, O[dt], 0, 0, 0);
    }
  }

  // ---- write out_perm (B,T,J,C): D col = d = dt*16+lr, row t = tw + lg*4 + reg ----
#pragma unroll
  for (int j = 0; j < 4; ++j) {
    const int t = tw + lg * 4 + j;
    float* orow = out_perm + ((size_t)((b * 256 + t) * 17 + jj)) * 512 + h * 64;
#pragma unroll
    for (int dt = 0; dt < 4; ++dt) {
      orow[dt * 16 + lr] = O[dt][j];
    }
  }
}

// ---------------- K4: d_out = out_perm @ w_proj + b_proj ----------------
__global__ __launch_bounds__(256) void proj_gemm(
    const float* __restrict__ A, const float* __restrict__ w,
    const float* __restrict__ bias, float* __restrict__ out) {
  __shared__ float As[16][64];
  __shared__ float Bs[16][64];
  const int tid = threadIdx.x;
  const int bm = blockIdx.x, bn = blockIdx.y;
  const int ty = tid >> 4, tx = tid & 15;
  const int arow = tid >> 2, akq = tid & 3;
  const int bkk = tid >> 4, bnq = tid & 15;
  const float* arp = A + (bm * 64 + arow) * 512 + akq * 4;
  const float* wcol = w + bn * 64 + bnq * 4;
  float acc[4][4];
#pragma unroll
  for (int i = 0; i < 4; ++i)
#pragma unroll
    for (int jj = 0; jj < 4; ++jj) acc[i][jj] = 0.f;

  for (int k0 = 0; k0 < 512; k0 += 16) {
    float4 a4 = *(const float4*)(arp + k0);
    float4 b4 = *(const float4*)(wcol + (size_t)(k0 + bkk) * 512);
    As[akq * 4 + 0][arow] = a4.x;
    As[akq * 4 + 1][arow] = a4.y;
    As[akq * 4 + 2][arow] = a4.z;
    As[akq * 4 + 3][arow] = a4.w;
    *(float4*)&Bs[bkk][bnq * 4] = b4;
    __syncthreads();
#pragma unroll
    for (int kk = 0; kk < 16; ++kk) {
      float4 av = *(const float4*)&As[kk][ty * 4];
      float4 bv = *(const float4*)&Bs[kk][tx * 4];
      float a[4] = {av.x, av.y, av.z, av.w};
      float bb[4] = {bv.x, bv.y, bv.z, bv.w};
#pragma unroll
      for (int i = 0; i < 4; ++i)
#pragma unroll
        for (int jj = 0; jj < 4; ++jj) acc[i][jj] += a[i] * bb[jj];
    }
    __syncthreads();
  }
  const int cbase = bn * 64 + tx * 4;
  float4 bi = *(const float4*)&bias[cbase];
#pragma unroll
  for (int i = 0; i < 4; ++i) {
    const int r = bm * 64 + ty * 4 + i;
    float4 o = make_float4(acc[i][0] + bi.x, acc[i][1] + bi.y, acc[i][2] + bi.z,
                           acc[i][3] + bi.w);
    *(float4*)&out[(size_t)r * 512 + cbase] = o;
  }
}

extern "C" void kernel_launch(void* const* d_in, const int* in_sizes, int n_in,
                              void* d_out, int out_size, void* d_ws, size_t ws_size,
                              hipStream_t stream) {
  (void)in_sizes; (void)n_in; (void)out_size; (void)ws_size;
  const float* x = (const float*)d_in[0];
  const float* att_map = (const float*)d_in[1];
  const float* weight = (const float*)d_in[2];
  const float* w_qkv = (const float*)d_in[3];
  const float* w_proj = (const float*)d_in[4];
  const float* b_proj = (const float*)d_in[5];
  const float* fgate = (const float*)d_in[6];
  float* out = (float*)d_out;

  char* ws = (char*)d_ws;
  const size_t HB = 35651584;  // 544*16384 f32 bytes
  float* qb = (float*)(ws);
  float* kb = (float*)(ws + HB);
  float* vb = (float*)(ws + 2 * HB);
  float* af = (float*)(ws + 3 * HB);
  float* out_perm = (float*)(ws + 3 * HB + 8912896);

  qkv_gemm<<<dim3(272, 24), 256, 0, stream>>>(x, w_qkv, qb, kb, vb);
  freq_kernel<<<544, 256, 0, stream>>>(qb, kb, af);
  attn_kernel<<<dim3(4, 544), 256, 0, stream>>>(qb, kb, vb, af, att_map, weight,
                                                fgate, out_perm);
  proj_gemm<<<dim3(272, 8), 256, 0, stream>>>(out_perm, w_proj, b_proj, out);
}

// Round 4
// 731.654 us; speedup vs baseline: 2.2024x; 1.4632x over previous
//
#include <hip/hip_runtime.h>
#include <hip/hip_bf16.h>

// FrequencyAwareSumAttention — round 4: split-precision MFMA DFT (K2).
// K1 qkv GEMM (fp32) -> q,k,v fp32 head-major [head][t][d]   (unchanged)
// K2 MFMA hi/lo-bf16 DFT (E 64x256 shared matrix) + MFMA af GEMM + softmax
// K3 MFMA bf16 attention (unchanged)
// K4 proj GEMM + bias (unchanged)

#define SCALE 0.125f

typedef __attribute__((ext_vector_type(4))) float f32x4;
typedef __attribute__((ext_vector_type(8))) short bf16x8;

__device__ __forceinline__ float bf2f(unsigned short u) {
  return __uint_as_float(((unsigned int)u) << 16);
}
__device__ __forceinline__ unsigned short f2bf(float f) {
  unsigned int u = __float_as_uint(f);
  u += 0x7FFFu + ((u >> 16) & 1u);
  return (unsigned short)(u >> 16);
}

// ---------------- K1: qkv = x @ w_qkv, scatter fp32 head-major ----------------
__global__ __launch_bounds__(256) void qkv_gemm(
    const float* __restrict__ x, const float* __restrict__ w,
    float* __restrict__ q, float* __restrict__ k, float* __restrict__ v) {
  __shared__ float As[16][64];
  __shared__ float Bs[16][64];
  const int tid = threadIdx.x;
  const int bm = blockIdx.x, bn = blockIdx.y;
  const int ty = tid >> 4, tx = tid & 15;
  const int arow = tid >> 2, akq = tid & 3;
  const int bkk = tid >> 4, bnq = tid & 15;
  const float* xrow = x + (bm * 64 + arow) * 512 + akq * 4;
  const float* wcol = w + bn * 64 + bnq * 4;
  float acc[4][4];
#pragma unroll
  for (int i = 0; i < 4; ++i)
#pragma unroll
    for (int jj = 0; jj < 4; ++jj) acc[i][jj] = 0.f;

  for (int k0 = 0; k0 < 512; k0 += 16) {
    float4 a4 = *(const float4*)(xrow + k0);
    float4 b4 = *(const float4*)(wcol + (size_t)(k0 + bkk) * 1536);
    As[akq * 4 + 0][arow] = a4.x;
    As[akq * 4 + 1][arow] = a4.y;
    As[akq * 4 + 2][arow] = a4.z;
    As[akq * 4 + 3][arow] = a4.w;
    *(float4*)&Bs[bkk][bnq * 4] = b4;
    __syncthreads();
#pragma unroll
    for (int kk = 0; kk < 16; ++kk) {
      float4 av = *(const float4*)&As[kk][ty * 4];
      float4 bv = *(const float4*)&Bs[kk][tx * 4];
      float a[4] = {av.x, av.y, av.z, av.w};
      float bb[4] = {bv.x, bv.y, bv.z, bv.w};
#pragma unroll
      for (int i = 0; i < 4; ++i)
#pragma unroll
        for (int jj = 0; jj < 4; ++jj) acc[i][jj] += a[i] * bb[jj];
    }
    __syncthreads();
  }
  const int cbase = bn * 64 + tx * 4;
  const int qi = cbase >> 9;
  const int h = (cbase >> 6) & 7;
  const int ddb = cbase & 63;
  float* dst = (qi == 0) ? q : (qi == 1) ? k : v;
#pragma unroll
  for (int i = 0; i < 4; ++i) {
    int r = bm * 64 + ty * 4 + i;
    int j = r % 17;
    int bt = r / 17;
    int t = bt & 255;
    int b = bt >> 8;
    int base = ((b * 8 + h) * 17 + j) * 16384 + t * 64 + ddb;
    *(float4*)&dst[base] = make_float4(acc[i][0], acc[i][1], acc[i][2], acc[i][3]);
  }
}

// ---------------- K2: split-precision MFMA DFT + af GEMM + freq softmax ----------------
// block = 256 thr (4 waves), one head. Wave w owns f-stripe [w*16, w*16+16).
// DFT: QF[f][d] = sum_t E[f][t] * q[t][d]  (E = cos / sin of 2*pi*f*t/256)
// Split precision: X ~= Xh + Xl (bf16 each); X*Y ~= Xh*Yh + Xh*Yl + Xl*Yh.
__global__ __launch_bounds__(256) void freq_kernel(
    const float* __restrict__ qg, const float* __restrict__ kg,
    float* __restrict__ af_out) {
  // qT: [h/l][d][t] bf16, swizzled: byte = d*512 + ((t*2) ^ ((d&31)<<4))
  __shared__ __attribute__((aligned(16))) unsigned short qT[2][64 * 256];
  // QF/KF: [rh,rl,ih,il][f][d] bf16, swizzled: byte = f*128 + ((d*2) ^ ((f&7)<<4))
  __shared__ __attribute__((aligned(16))) unsigned short QF[4][64 * 64];
  __shared__ __attribute__((aligned(16))) unsigned short KF[4][64 * 64];

  const int tid = threadIdx.x;
  const int head = blockIdx.x;
  const int w = tid >> 6, lane = tid & 63;
  const int lr = lane & 15, lg = lane >> 4;
  const int f0 = w << 4;

  // ---- E fragments (A-side), computed once per wave, reused for q and k ----
  // A layout: m = lane&15 -> f = f0+lr ; k = (lane>>4)*8+i -> t = kb*32+lg*8+i
  bf16x8 Ech[8], Ecl[8], Esh[8], Esl[8];
  {
    const int f = f0 + lr;
#pragma unroll
    for (int kb = 0; kb < 8; ++kb) {
      bf16x8 ch, cl, sh, sl;
#pragma unroll
      for (int i = 0; i < 8; ++i) {
        int t = kb * 32 + lg * 8 + i;
        int idx = (f * t) & 255;
        float s, c;
        __sincosf((float)idx * 0.02454369260617026f, &s, &c);
        unsigned short chh = f2bf(c);
        unsigned short shh = f2bf(s);
        ch[i] = (short)chh;
        cl[i] = (short)f2bf(c - bf2f(chh));
        sh[i] = (short)shh;
        sl[i] = (short)f2bf(s - bf2f(shh));
      }
      Ech[kb] = ch; Ecl[kb] = cl; Esh[kb] = sh; Esl[kb] = sl;
    }
  }

  // ---- two passes: q -> QF, k -> KF ----
  for (int pass = 0; pass < 2; ++pass) {
    const float* src = pass ? kg : qg;
    __syncthreads();  // pass 1: wait until all waves finished reading qT
    const float4* s4 = (const float4*)(src + head * 16384);
    for (int i = tid; i < 4096; i += 256) {
      int t = i >> 4, dq = i & 15;
      float4 v4 = s4[i];
      float vv[4] = {v4.x, v4.y, v4.z, v4.w};
#pragma unroll
      for (int c = 0; c < 4; ++c) {
        int d = dq * 4 + c;
        unsigned short hi = f2bf(vv[c]);
        unsigned short lo = f2bf(vv[c] - bf2f(hi));
        int byo = d * 512 + ((t * 2) ^ ((d & 31) << 4));
        *(unsigned short*)((char*)qT[0] + byo) = hi;
        *(unsigned short*)((char*)qT[1] + byo) = lo;
      }
    }
    __syncthreads();

    // DFT MFMA: stripe f0..f0+15 (M) x d 0..63 (N), K = 256 over t
    f32x4 ar[4], ai[4];
#pragma unroll
    for (int nt = 0; nt < 4; ++nt) {
      ar[nt] = (f32x4){0.f, 0.f, 0.f, 0.f};
      ai[nt] = (f32x4){0.f, 0.f, 0.f, 0.f};
    }
#pragma unroll
    for (int kb = 0; kb < 8; ++kb) {
#pragma unroll
      for (int nt = 0; nt < 4; ++nt) {
        const int d = nt * 16 + lr;  // B: n = lane&15
        const int byo = d * 512 + ((kb * 64 + lg * 16) ^ ((d & 31) << 4));
        bf16x8 bh = *(bf16x8*)((char*)qT[0] + byo);
        bf16x8 bl = *(bf16x8*)((char*)qT[1] + byo);
        ar[nt] = __builtin_amdgcn_mfma_f32_16x16x32_bf16(Ech[kb], bh, ar[nt], 0, 0, 0);
        ar[nt] = __builtin_amdgcn_mfma_f32_16x16x32_bf16(Ech[kb], bl, ar[nt], 0, 0, 0);
        ar[nt] = __builtin_amdgcn_mfma_f32_16x16x32_bf16(Ecl[kb], bh, ar[nt], 0, 0, 0);
        ai[nt] = __builtin_amdgcn_mfma_f32_16x16x32_bf16(Esh[kb], bh, ai[nt], 0, 0, 0);
        ai[nt] = __builtin_amdgcn_mfma_f32_16x16x32_bf16(Esh[kb], bl, ai[nt], 0, 0, 0);
        ai[nt] = __builtin_amdgcn_mfma_f32_16x16x32_bf16(Esl[kb], bh, ai[nt], 0, 0, 0);
      }
    }
    // write stripe to QF/KF split hi/lo; D: row f = f0+lg*4+j, col d = nt*16+lr
    unsigned short(*DST)[64 * 64] = pass ? KF : QF;
#pragma unroll
    for (int nt = 0; nt < 4; ++nt) {
#pragma unroll
      for (int j = 0; j < 4; ++j) {
        const int f = f0 + lg * 4 + j;
        const int d = nt * 16 + lr;
        const int byo = f * 128 + ((d * 2) ^ ((f & 7) << 4));
        float vr = ar[nt][j], vi = ai[nt][j];
        unsigned short rh = f2bf(vr);
        unsigned short ih = f2bf(vi);
        *(unsigned short*)((char*)DST[0] + byo) = rh;
        *(unsigned short*)((char*)DST[1] + byo) = f2bf(vr - bf2f(rh));
        *(unsigned short*)((char*)DST[2] + byo) = ih;
        *(unsigned short*)((char*)DST[3] + byo) = f2bf(vi - bf2f(ih));
      }
    }
  }
  __syncthreads();

  // ---- af GEMM: af[f][g] = QFr.KFr + QFi.KFi (K=64 per r/i), split precision ----
  f32x4 acc[4];
#pragma unroll
  for (int nt = 0; nt < 4; ++nt) acc[nt] = (f32x4){0.f, 0.f, 0.f, 0.f};
#pragma unroll
  for (int kb = 0; kb < 2; ++kb) {
    const int fA = f0 + lr;  // A: m = lane&15
    const int abyo = fA * 128 + ((kb * 64 + lg * 16) ^ ((fA & 7) << 4));
    bf16x8 arh = *(bf16x8*)((char*)QF[0] + abyo);
    bf16x8 arl = *(bf16x8*)((char*)QF[1] + abyo);
    bf16x8 aih = *(bf16x8*)((char*)QF[2] + abyo);
    bf16x8 ail = *(bf16x8*)((char*)QF[3] + abyo);
#pragma unroll
    for (int nt = 0; nt < 4; ++nt) {
      const int g = nt * 16 + lr;  // B: n = lane&15
      const int bbyo = g * 128 + ((kb * 64 + lg * 16) ^ ((g & 7) << 4));
      bf16x8 brh = *(bf16x8*)((char*)KF[0] + bbyo);
      bf16x8 brl = *(bf16x8*)((char*)KF[1] + bbyo);
      bf16x8 bih = *(bf16x8*)((char*)KF[2] + bbyo);
      bf16x8 bil = *(bf16x8*)((char*)KF[3] + bbyo);
      acc[nt] = __builtin_amdgcn_mfma_f32_16x16x32_bf16(arh, brh, acc[nt], 0, 0, 0);
      acc[nt] = __builtin_amdgcn_mfma_f32_16x16x32_bf16(arh, brl, acc[nt], 0, 0, 0);
      acc[nt] = __builtin_amdgcn_mfma_f32_16x16x32_bf16(arl, brh, acc[nt], 0, 0, 0);
      acc[nt] = __builtin_amdgcn_mfma_f32_16x16x32_bf16(aih, bih, acc[nt], 0, 0, 0);
      acc[nt] = __builtin_amdgcn_mfma_f32_16x16x32_bf16(aih, bil, acc[nt], 0, 0, 0);
      acc[nt] = __builtin_amdgcn_mfma_f32_16x16x32_bf16(ail, bih, acc[nt], 0, 0, 0);
    }
  }

  // ---- softmax over g (64 = 4 in-reg x 16 lanes of lr-group) + store fp32 ----
  float* outh = af_out + head * 4096;
#pragma unroll
  for (int j = 0; j < 4; ++j) {
    float m = fmaxf(fmaxf(acc[0][j], acc[1][j]), fmaxf(acc[2][j], acc[3][j]));
#pragma unroll
    for (int mask = 1; mask < 16; mask <<= 1) m = fmaxf(m, __shfl_xor(m, mask));
    float e[4];
    float rs = 0.f;
#pragma unroll
    for (int nt = 0; nt < 4; ++nt) {
      e[nt] = __expf((acc[nt][j] - m) * SCALE);
      rs += e[nt];
    }
#pragma unroll
    for (int mask = 1; mask < 16; mask <<= 1) rs += __shfl_xor(rs, mask);
    const float inv = 1.0f / rs;
    const int f = f0 + lg * 4 + j;
#pragma unroll
    for (int nt = 0; nt < 4; ++nt) outh[f * 64 + nt * 16 + lr] = e[nt] * inv;
  }
}

// ---------------- K3: MFMA attention (unchanged, verified) ----------------
__global__ __launch_bounds__(256) void attn_kernel(
    const float* __restrict__ qg, const float* __restrict__ kg,
    const float* __restrict__ vg, const float* __restrict__ af,
    const float* __restrict__ att_map, const float* __restrict__ weight,
    const float* __restrict__ fgate, float* __restrict__ out_perm) {
  __shared__ unsigned short Ks[256 * 64];
  __shared__ unsigned short Vt[64 * 256];
  __shared__ unsigned short afl[64 * 66];
  __shared__ unsigned short Psc[4][16 * 40];

  const int tid = threadIdx.x;
  const int t0 = blockIdx.x << 6;
  const int head = blockIdx.y;
  const int jj = head % 17;
  const int hb = head / 17;
  const int h = hb & 7;
  const int b = hb >> 3;

  const float4* ksrc = (const float4*)(kg + head * 16384);
  const float4* vsrc = (const float4*)(vg + head * 16384);
  for (int i = tid; i < 4096; i += 256) {
    int s = i >> 4, dq = i & 15;
    float4 kf = ksrc[i];
    ushort4 k4 = make_ushort4(f2bf(kf.x), f2bf(kf.y), f2bf(kf.z), f2bf(kf.w));
    int koff = s * 128 + ((dq * 8) ^ ((s & 7) << 4));
    *(ushort4*)((char*)Ks + koff) = k4;
    float4 vf = vsrc[i];
    float vv[4] = {vf.x, vf.y, vf.z, vf.w};
#pragma unroll
    for (int c = 0; c < 4; ++c) {
      int d = dq * 4 + c;
      int voff = d * 512 + ((s * 2) ^ ((d & 7) << 4));
      *(unsigned short*)((char*)Vt + voff) = f2bf(vv[c]);
    }
  }
  const float4* asrc = (const float4*)(af + head * 4096);
  for (int i = tid; i < 1024; i += 256) {
    float4 a4 = asrc[i];
    int f = i >> 4, gq = (i & 15) << 2;
    ushort4 a4b = make_ushort4(f2bf(a4.x), f2bf(a4.y), f2bf(a4.z), f2bf(a4.w));
    *(ushort4*)&afl[f * 66 + gq] = a4b;
  }
  __syncthreads();

  const int w = tid >> 6, lane = tid & 63;
  const int lr = lane & 15, lg = lane >> 4;
  const int tw = t0 + w * 16;

  bf16x8 aq[2];
  {
    const float* qrow = qg + head * 16384 + (tw + lr) * 64 + lg * 8;
#pragma unroll
    for (int kc = 0; kc < 2; ++kc) {
      float4 q0 = *(const float4*)(qrow + kc * 32);
      float4 q1 = *(const float4*)(qrow + kc * 32 + 4);
      bf16x8 a;
      a[0] = (short)f2bf(q0.x); a[1] = (short)f2bf(q0.y);
      a[2] = (short)f2bf(q0.z); a[3] = (short)f2bf(q0.w);
      a[4] = (short)f2bf(q1.x); a[5] = (short)f2bf(q1.y);
      a[6] = (short)f2bf(q1.z); a[7] = (short)f2bf(q1.w);
      aq[kc] = a;
    }
  }

  f32x4 S[16];
#pragma unroll
  for (int nt = 0; nt < 16; ++nt) {
    f32x4 accv = {0.f, 0.f, 0.f, 0.f};
#pragma unroll
    for (int kc = 0; kc < 2; ++kc) {
      int srow = nt * 16 + lr;
      int d0 = kc * 32 + lg * 8;
      int off = srow * 128 + ((d0 * 2) ^ ((srow & 7) << 4));
      bf16x8 bk = *(bf16x8*)((char*)Ks + off);
      accv = __builtin_amdgcn_mfma_f32_16x16x32_bf16(aq[kc], bk, accv, 0, 0, 0);
    }
    S[nt] = accv;
  }

  float inv[4], mrow[4];
#pragma unroll
  for (int j = 0; j < 4; ++j) {
    float m = -1e30f;
#pragma unroll
    for (int nt = 0; nt < 16; ++nt) m = fmaxf(m, S[nt][j]);
#pragma unroll
    for (int mask = 1; mask < 16; mask <<= 1) m = fmaxf(m, __shfl_xor(m, mask));
    mrow[j] = m;
  }
#pragma unroll
  for (int j = 0; j < 4; ++j) {
    float rs = 0.f;
#pragma unroll
    for (int nt = 0; nt < 16; ++nt) {
      float e = __expf((S[nt][j] - mrow[j]) * SCALE);
      S[nt][j] = e;
      rs += e;
    }
#pragma unroll
    for (int mask = 1; mask < 16; mask <<= 1) rs += __shfl_xor(rs, mask);
    inv[j] = 1.0f / rs;
  }

  {
    const float wv = weight[0];
    const float gate = 1.0f / (1.0f + __expf(-fgate[0]));
    const float* amh = att_map + (size_t)head * 65536;
#pragma unroll
    for (int j = 0; j < 4; ++j) {
      const int t = tw + lg * 4 + j;
      float srcf = fmaxf((t + 0.5f) * (129.0f / 256.0f) - 0.5f, 0.0f);
      int f0r = (int)srcf;
      float wf = srcf - (float)f0r;
      int f1r = f0r + 1;
      if (f1r > 128) f1r = 128;
      const bool v0 = (f0r < 64), v1 = (f1r < 64);
#pragma unroll
      for (int nt = 0; nt < 16; ++nt) {
        const int s = nt * 16 + lr;
        float am = amh[t * 256 + s];
        float srcg = fmaxf((s + 0.5f) * 0.25f - 0.5f, 0.0f);
        int g0 = (int)srcg;
        float wc = srcg - (float)g0;
        int g1 = g0 + 1;
        if (g1 > 63) g1 = 63;
        float fr = 0.f;
        if (v0)
          fr += (1.0f - wf) *
                (bf2f(afl[f0r * 66 + g0]) * (1.0f - wc) + bf2f(afl[f0r * 66 + g1]) * wc);
        if (v1)
          fr += wf *
                (bf2f(afl[f1r * 66 + g0]) * (1.0f - wc) + bf2f(afl[f1r * 66 + g1]) * wc);
        float pt = S[nt][j] * inv[j];
        S[nt][j] = wv * (gate * fr + (1.0f - gate) * pt) + (1.0f - wv) * am;
      }
    }
  }

  f32x4 O[4];
#pragma unroll
  for (int dt = 0; dt < 4; ++dt) O[dt] = (f32x4){0.f, 0.f, 0.f, 0.f};
  unsigned short* psc = Psc[w];
#pragma unroll
  for (int sb = 0; sb < 8; ++sb) {
#pragma unroll
    for (int half = 0; half < 2; ++half) {
      const int nt = sb * 2 + half;
#pragma unroll
      for (int j = 0; j < 4; ++j) {
        psc[(lg * 4 + j) * 40 + half * 16 + lr] = f2bf(S[nt][j]);
      }
    }
    bf16x8 pa = *(bf16x8*)&psc[lr * 40 + lg * 8];
#pragma unroll
    for (int dt = 0; dt < 4; ++dt) {
      int d = dt * 16 + lr;
      int s0 = sb * 32 + lg * 8;
      int off = d * 512 + ((s0 * 2) ^ ((d & 7) << 4));
      bf16x8 bv = *(bf16x8*)((char*)Vt + off);
      O[dt] = __builtin_amdgcn_mfma_f32_16x16x32_bf16(pa, bv, O[dt], 0, 0, 0);
    }
  }

#pragma unroll
  for (int j = 0; j < 4; ++j) {
    const int t = tw + lg * 4 + j;
    float* orow = out_perm + ((size_t)((b * 256 + t) * 17 + jj)) * 512 + h * 64;
#pragma unroll
    for (int dt = 0; dt < 4; ++dt) {
      orow[dt * 16 + lr] = O[dt][j];
    }
  }
}

// ---------------- K4: d_out = out_perm @ w_proj + b_proj ----------------
__global__ __launch_bounds__(256) void proj_gemm(
    const float* __restrict__ A, const float* __restrict__ w,
    const float* __restrict__ bias, float* __restrict__ out) {
  __shared__ float As[16][64];
  __shared__ float Bs[16][64];
  const int tid = threadIdx.x;
  const int bm = blockIdx.x, bn = blockIdx.y;
  const int ty = tid >> 4, tx = tid & 15;
  const int arow = tid >> 2, akq = tid & 3;
  const int bkk = tid >> 4, bnq = tid & 15;
  const float* arp = A + (bm * 64 + arow) * 512 + akq * 4;
  const float* wcol = w + bn * 64 + bnq * 4;
  float acc[4][4];
#pragma unroll
  for (int i = 0; i < 4; ++i)
#pragma unroll
    for (int jj = 0; jj < 4; ++jj) acc[i][jj] = 0.f;

  for (int k0 = 0; k0 < 512; k0 += 16) {
    float4 a4 = *(const float4*)(arp + k0);
    float4 b4 = *(const float4*)(wcol + (size_t)(k0 + bkk) * 512);
    As[akq * 4 + 0][arow] = a4.x;
    As[akq * 4 + 1][arow] = a4.y;
    As[akq * 4 + 2][arow] = a4.z;
    As[akq * 4 + 3][arow] = a4.w;
    *(float4*)&Bs[bkk][bnq * 4] = b4;
    __syncthreads();
#pragma unroll
    for (int kk = 0; kk < 16; ++kk) {
      float4 av = *(const float4*)&As[kk][ty * 4];
      float4 bv = *(const float4*)&Bs[kk][tx * 4];
      float a[4] = {av.x, av.y, av.z, av.w};
      float bb[4] = {bv.x, bv.y, bv.z, bv.w};
#pragma unroll
      for (int i = 0; i < 4; ++i)
#pragma unroll
        for (int jj = 0; jj < 4; ++jj) acc[i][jj] += a[i] * bb[jj];
    }
    __syncthreads();
  }
  const int cbase = bn * 64 + tx * 4;
  float4 bi = *(const float4*)&bias[cbase];
#pragma unroll
  for (int i = 0; i < 4; ++i) {
    const int r = bm * 64 + ty * 4 + i;
    float4 o = make_float4(acc[i][0] + bi.x, acc[i][1] + bi.y, acc[i][2] + bi.z,
                           acc[i][3] + bi.w);
    *(float4*)&out[(size_t)r * 512 + cbase] = o;
  }
}

extern "C" void kernel_launch(void* const* d_in, const int* in_sizes, int n_in,
                              void* d_out, int out_size, void* d_ws, size_t ws_size,
                              hipStream_t stream) {
  (void)in_sizes; (void)n_in; (void)out_size; (void)ws_size;
  const float* x = (const float*)d_in[0];
  const float* att_map = (const float*)d_in[1];
  const float* weight = (const float*)d_in[2];
  const float* w_qkv = (const float*)d_in[3];
  const float* w_proj = (const float*)d_in[4];
  const float* b_proj = (const float*)d_in[5];
  const float* fgate = (const float*)d_in[6];
  float* out = (float*)d_out;

  char* ws = (char*)d_ws;
  const size_t HB = 35651584;  // 544*16384 f32 bytes
  float* qb = (float*)(ws);
  float* kb = (float*)(ws + HB);
  float* vb = (float*)(ws + 2 * HB);
  float* af = (float*)(ws + 3 * HB);
  float* out_perm = (float*)(ws + 3 * HB + 8912896);

  qkv_gemm<<<dim3(272, 24), 256, 0, stream>>>(x, w_qkv, qb, kb, vb);
  freq_kernel<<<544, 256, 0, stream>>>(qb, kb, af);
  attn_kernel<<<dim3(4, 544), 256, 0, stream>>>(qb, kb, vb, af, att_map, weight,
                                                fgate, out_perm);
  proj_gemm<<<dim3(272, 8), 256, 0, stream>>>(out_perm, w_proj, b_proj, out);
}

// Round 5
// 684.344 us; speedup vs baseline: 2.3546x; 1.0691x over previous
//
#include <hip/hip_runtime.h>
#include <hip/hip_bf16.h>

// FrequencyAwareSumAttention — round 5: split-precision MFMA GEMMs (K1, K4).
// K1 split-bf16 MFMA qkv GEMM -> q,k,v fp32 head-major
// K2 split-bf16 MFMA DFT + af GEMM + softmax (unchanged)
// K3 MFMA bf16 attention (unchanged)
// K4 split-bf16 MFMA proj GEMM + bias

#define SCALE 0.125f

typedef __attribute__((ext_vector_type(4))) float f32x4;
typedef __attribute__((ext_vector_type(8))) short bf16x8;

__device__ __forceinline__ float bf2f(unsigned short u) {
  return __uint_as_float(((unsigned int)u) << 16);
}
__device__ __forceinline__ unsigned short f2bf(float f) {
  unsigned int u = __float_as_uint(f);
  u += 0x7FFFu + ((u >> 16) & 1u);
  return (unsigned short)(u >> 16);
}

// ---------------- K1: qkv = x @ w_qkv (split-bf16 MFMA), scatter fp32 head-major ----
// MFMA M-side = w_qkv columns (n), N-side = x rows (m).
// blockIdx.x = n-tile (1536/128 = 12), blockIdx.y = m-tile (17408/128 = 136).
__global__ __launch_bounds__(256, 2) void qkv_gemm(
    const float* __restrict__ x, const float* __restrict__ wq,
    float* __restrict__ q, float* __restrict__ k, float* __restrict__ v) {
  // W^T tile [n 128][k 64] hi/lo bf16, byte = n*128 + ((k*2) ^ ((n&7)<<4))
  __shared__ __attribute__((aligned(16))) unsigned short Wl[2][128 * 64];
  // X tile  [m 128][k 64] hi/lo bf16, same swizzle
  __shared__ __attribute__((aligned(16))) unsigned short Xl[2][128 * 64];

  const int tid = threadIdx.x;
  const int bx = blockIdx.x;
  const int by = blockIdx.y;
  const int wid = tid >> 6, lane = tid & 63;
  const int lr = lane & 15, lg = lane >> 4;
  const int wr = wid >> 1, wc = wid & 1;  // n-half, m-half

  f32x4 acc[4][4];
#pragma unroll
  for (int nt = 0; nt < 4; ++nt)
#pragma unroll
    for (int mt = 0; mt < 4; ++mt) acc[nt][mt] = (f32x4){0.f, 0.f, 0.f, 0.f};

  for (int k0 = 0; k0 < 512; k0 += 64) {
    // stage X: 128x64 fp32 -> hi/lo bf16 (2048 float4, coalesced)
#pragma unroll
    for (int i = 0; i < 8; ++i) {
      const int f4i = tid + 256 * i;
      const int row = f4i >> 4, cq = f4i & 15;  // row 0..127, col quad 0..15
      float4 v4 = *(const float4*)(x + (size_t)(by * 128 + row) * 512 + k0 + cq * 4);
      ushort4 hi, lo;
      hi.x = f2bf(v4.x); lo.x = f2bf(v4.x - bf2f(hi.x));
      hi.y = f2bf(v4.y); lo.y = f2bf(v4.y - bf2f(hi.y));
      hi.z = f2bf(v4.z); lo.z = f2bf(v4.z - bf2f(hi.z));
      hi.w = f2bf(v4.w); lo.w = f2bf(v4.w - bf2f(hi.w));
      const int byo = row * 128 + ((cq * 8) ^ ((row & 7) << 4));
      *(ushort4*)((char*)Xl[0] + byo) = hi;
      *(ushort4*)((char*)Xl[1] + byo) = lo;
    }
    // stage W transposed: 64(k) x 128(n) fp32 -> [n][k] hi/lo
#pragma unroll
    for (int i = 0; i < 8; ++i) {
      const int f4i = tid + 256 * i;
      const int kr = f4i >> 5, nq = f4i & 31;  // k-row 0..63, n quad 0..31
      float4 v4 = *(const float4*)(wq + (size_t)(k0 + kr) * 1536 + bx * 128 + nq * 4);
      float vv[4] = {v4.x, v4.y, v4.z, v4.w};
#pragma unroll
      for (int c = 0; c < 4; ++c) {
        const int n = nq * 4 + c;
        unsigned short hi = f2bf(vv[c]);
        unsigned short lo = f2bf(vv[c] - bf2f(hi));
        const int byo = n * 128 + ((kr * 2) ^ ((n & 7) << 4));
        *(unsigned short*)((char*)Wl[0] + byo) = hi;
        *(unsigned short*)((char*)Wl[1] + byo) = lo;
      }
    }
    __syncthreads();

#pragma unroll
    for (int kh = 0; kh < 2; ++kh) {
      const int kbase = kh * 32 + lg * 8;
      bf16x8 Ah[4], Al[4], Bh[4], Bl[4];
#pragma unroll
      for (int nt = 0; nt < 4; ++nt) {
        const int n = wr * 64 + nt * 16 + lr;
        const int byo = n * 128 + ((kbase * 2) ^ ((n & 7) << 4));
        Ah[nt] = *(bf16x8*)((char*)Wl[0] + byo);
        Al[nt] = *(bf16x8*)((char*)Wl[1] + byo);
      }
#pragma unroll
      for (int mt = 0; mt < 4; ++mt) {
        const int m = wc * 64 + mt * 16 + lr;
        const int byo = m * 128 + ((kbase * 2) ^ ((m & 7) << 4));
        Bh[mt] = *(bf16x8*)((char*)Xl[0] + byo);
        Bl[mt] = *(bf16x8*)((char*)Xl[1] + byo);
      }
#pragma unroll
      for (int nt = 0; nt < 4; ++nt)
#pragma unroll
        for (int mt = 0; mt < 4; ++mt) {
          acc[nt][mt] = __builtin_amdgcn_mfma_f32_16x16x32_bf16(Ah[nt], Bh[mt], acc[nt][mt], 0, 0, 0);
          acc[nt][mt] = __builtin_amdgcn_mfma_f32_16x16x32_bf16(Ah[nt], Bl[mt], acc[nt][mt], 0, 0, 0);
          acc[nt][mt] = __builtin_amdgcn_mfma_f32_16x16x32_bf16(Al[nt], Bh[mt], acc[nt][mt], 0, 0, 0);
        }
    }
    __syncthreads();
  }

  // epilogue: D col = m (x-row), D reg j -> n+j (w-col). float4 per acc.
#pragma unroll
  for (int mt = 0; mt < 4; ++mt) {
    const int m = by * 128 + wc * 64 + mt * 16 + lr;
    const int jj = m % 17;
    const int bt = m / 17;
    const int t = bt & 255;
    const int b = bt >> 8;
#pragma unroll
    for (int nt = 0; nt < 4; ++nt) {
      const int c = bx * 128 + wr * 64 + nt * 16 + lg * 4;
      const int qi = c >> 9;
      const int h = (c >> 6) & 7;
      const int dd = c & 63;
      float* dst = (qi == 0) ? q : (qi == 1) ? k : v;
      *(float4*)&dst[((size_t)((b * 8 + h) * 17 + jj)) * 16384 + t * 64 + dd] =
          make_float4(acc[nt][mt][0], acc[nt][mt][1], acc[nt][mt][2], acc[nt][mt][3]);
    }
  }
}

// ---------------- K2: split-precision MFMA DFT + af GEMM + freq softmax ----------------
__global__ __launch_bounds__(256) void freq_kernel(
    const float* __restrict__ qg, const float* __restrict__ kg,
    float* __restrict__ af_out) {
  __shared__ __attribute__((aligned(16))) unsigned short qT[2][64 * 256];
  __shared__ __attribute__((aligned(16))) unsigned short QF[4][64 * 64];
  __shared__ __attribute__((aligned(16))) unsigned short KF[4][64 * 64];

  const int tid = threadIdx.x;
  const int head = blockIdx.x;
  const int w = tid >> 6, lane = tid & 63;
  const int lr = lane & 15, lg = lane >> 4;
  const int f0 = w << 4;

  bf16x8 Ech[8], Ecl[8], Esh[8], Esl[8];
  {
    const int f = f0 + lr;
#pragma unroll
    for (int kb = 0; kb < 8; ++kb) {
      bf16x8 ch, cl, sh, sl;
#pragma unroll
      for (int i = 0; i < 8; ++i) {
        int t = kb * 32 + lg * 8 + i;
        int idx = (f * t) & 255;
        float s, c;
        __sincosf((float)idx * 0.02454369260617026f, &s, &c);
        unsigned short chh = f2bf(c);
        unsigned short shh = f2bf(s);
        ch[i] = (short)chh;
        cl[i] = (short)f2bf(c - bf2f(chh));
        sh[i] = (short)shh;
        sl[i] = (short)f2bf(s - bf2f(shh));
      }
      Ech[kb] = ch; Ecl[kb] = cl; Esh[kb] = sh; Esl[kb] = sl;
    }
  }

  for (int pass = 0; pass < 2; ++pass) {
    const float* src = pass ? kg : qg;
    __syncthreads();
    const float4* s4 = (const float4*)(src + head * 16384);
    for (int i = tid; i < 4096; i += 256) {
      int t = i >> 4, dq = i & 15;
      float4 v4 = s4[i];
      float vv[4] = {v4.x, v4.y, v4.z, v4.w};
#pragma unroll
      for (int c = 0; c < 4; ++c) {
        int d = dq * 4 + c;
        unsigned short hi = f2bf(vv[c]);
        unsigned short lo = f2bf(vv[c] - bf2f(hi));
        int byo = d * 512 + ((t * 2) ^ ((d & 31) << 4));
        *(unsigned short*)((char*)qT[0] + byo) = hi;
        *(unsigned short*)((char*)qT[1] + byo) = lo;
      }
    }
    __syncthreads();

    f32x4 ar[4], ai[4];
#pragma unroll
    for (int nt = 0; nt < 4; ++nt) {
      ar[nt] = (f32x4){0.f, 0.f, 0.f, 0.f};
      ai[nt] = (f32x4){0.f, 0.f, 0.f, 0.f};
    }
#pragma unroll
    for (int kb = 0; kb < 8; ++kb) {
#pragma unroll
      for (int nt = 0; nt < 4; ++nt) {
        const int d = nt * 16 + lr;
        const int byo = d * 512 + ((kb * 64 + lg * 16) ^ ((d & 31) << 4));
        bf16x8 bh = *(bf16x8*)((char*)qT[0] + byo);
        bf16x8 bl = *(bf16x8*)((char*)qT[1] + byo);
        ar[nt] = __builtin_amdgcn_mfma_f32_16x16x32_bf16(Ech[kb], bh, ar[nt], 0, 0, 0);
        ar[nt] = __builtin_amdgcn_mfma_f32_16x16x32_bf16(Ech[kb], bl, ar[nt], 0, 0, 0);
        ar[nt] = __builtin_amdgcn_mfma_f32_16x16x32_bf16(Ecl[kb], bh, ar[nt], 0, 0, 0);
        ai[nt] = __builtin_amdgcn_mfma_f32_16x16x32_bf16(Esh[kb], bh, ai[nt], 0, 0, 0);
        ai[nt] = __builtin_amdgcn_mfma_f32_16x16x32_bf16(Esh[kb], bl, ai[nt], 0, 0, 0);
        ai[nt] = __builtin_amdgcn_mfma_f32_16x16x32_bf16(Esl[kb], bh, ai[nt], 0, 0, 0);
      }
    }
    unsigned short(*DST)[64 * 64] = pass ? KF : QF;
#pragma unroll
    for (int nt = 0; nt < 4; ++nt) {
#pragma unroll
      for (int j = 0; j < 4; ++j) {
        const int f = f0 + lg * 4 + j;
        const int d = nt * 16 + lr;
        const int byo = f * 128 + ((d * 2) ^ ((f & 7) << 4));
        float vr = ar[nt][j], vi = ai[nt][j];
        unsigned short rh = f2bf(vr);
        unsigned short ih = f2bf(vi);
        *(unsigned short*)((char*)DST[0] + byo) = rh;
        *(unsigned short*)((char*)DST[1] + byo) = f2bf(vr - bf2f(rh));
        *(unsigned short*)((char*)DST[2] + byo) = ih;
        *(unsigned short*)((char*)DST[3] + byo) = f2bf(vi - bf2f(ih));
      }
    }
  }
  __syncthreads();

  f32x4 acc[4];
#pragma unroll
  for (int nt = 0; nt < 4; ++nt) acc[nt] = (f32x4){0.f, 0.f, 0.f, 0.f};
#pragma unroll
  for (int kb = 0; kb < 2; ++kb) {
    const int fA = f0 + lr;
    const int abyo = fA * 128 + ((kb * 64 + lg * 16) ^ ((fA & 7) << 4));
    bf16x8 arh = *(bf16x8*)((char*)QF[0] + abyo);
    bf16x8 arl = *(bf16x8*)((char*)QF[1] + abyo);
    bf16x8 aih = *(bf16x8*)((char*)QF[2] + abyo);
    bf16x8 ail = *(bf16x8*)((char*)QF[3] + abyo);
#pragma unroll
    for (int nt = 0; nt < 4; ++nt) {
      const int g = nt * 16 + lr;
      const int bbyo = g * 128 + ((kb * 64 + lg * 16) ^ ((g & 7) << 4));
      bf16x8 brh = *(bf16x8*)((char*)KF[0] + bbyo);
      bf16x8 brl = *(bf16x8*)((char*)KF[1] + bbyo);
      bf16x8 bih = *(bf16x8*)((char*)KF[2] + bbyo);
      bf16x8 bil = *(bf16x8*)((char*)KF[3] + bbyo);
      acc[nt] = __builtin_amdgcn_mfma_f32_16x16x32_bf16(arh, brh, acc[nt], 0, 0, 0);
      acc[nt] = __builtin_amdgcn_mfma_f32_16x16x32_bf16(arh, brl, acc[nt], 0, 0, 0);
      acc[nt] = __builtin_amdgcn_mfma_f32_16x16x32_bf16(arl, brh, acc[nt], 0, 0, 0);
      acc[nt] = __builtin_amdgcn_mfma_f32_16x16x32_bf16(aih, bih, acc[nt], 0, 0, 0);
      acc[nt] = __builtin_amdgcn_mfma_f32_16x16x32_bf16(aih, bil, acc[nt], 0, 0, 0);
      acc[nt] = __builtin_amdgcn_mfma_f32_16x16x32_bf16(ail, bih, acc[nt], 0, 0, 0);
    }
  }

  float* outh = af_out + head * 4096;
#pragma unroll
  for (int j = 0; j < 4; ++j) {
    float m = fmaxf(fmaxf(acc[0][j], acc[1][j]), fmaxf(acc[2][j], acc[3][j]));
#pragma unroll
    for (int mask = 1; mask < 16; mask <<= 1) m = fmaxf(m, __shfl_xor(m, mask));
    float e[4];
    float rs = 0.f;
#pragma unroll
    for (int nt = 0; nt < 4; ++nt) {
      e[nt] = __expf((acc[nt][j] - m) * SCALE);
      rs += e[nt];
    }
#pragma unroll
    for (int mask = 1; mask < 16; mask <<= 1) rs += __shfl_xor(rs, mask);
    const float inv = 1.0f / rs;
    const int f = f0 + lg * 4 + j;
#pragma unroll
    for (int nt = 0; nt < 4; ++nt) outh[f * 64 + nt * 16 + lr] = e[nt] * inv;
  }
}

// ---------------- K3: MFMA attention (unchanged, verified) ----------------
__global__ __launch_bounds__(256) void attn_kernel(
    const float* __restrict__ qg, const float* __restrict__ kg,
    const float* __restrict__ vg, const float* __restrict__ af,
    const float* __restrict__ att_map, const float* __restrict__ weight,
    const float* __restrict__ fgate, float* __restrict__ out_perm) {
  __shared__ unsigned short Ks[256 * 64];
  __shared__ unsigned short Vt[64 * 256];
  __shared__ unsigned short afl[64 * 66];
  __shared__ unsigned short Psc[4][16 * 40];

  const int tid = threadIdx.x;
  const int t0 = blockIdx.x << 6;
  const int head = blockIdx.y;
  const int jj = head % 17;
  const int hb = head / 17;
  const int h = hb & 7;
  const int b = hb >> 3;

  const float4* ksrc = (const float4*)(kg + head * 16384);
  const float4* vsrc = (const float4*)(vg + head * 16384);
  for (int i = tid; i < 4096; i += 256) {
    int s = i >> 4, dq = i & 15;
    float4 kf = ksrc[i];
    ushort4 k4 = make_ushort4(f2bf(kf.x), f2bf(kf.y), f2bf(kf.z), f2bf(kf.w));
    int koff = s * 128 + ((dq * 8) ^ ((s & 7) << 4));
    *(ushort4*)((char*)Ks + koff) = k4;
    float4 vf = vsrc[i];
    float vv[4] = {vf.x, vf.y, vf.z, vf.w};
#pragma unroll
    for (int c = 0; c < 4; ++c) {
      int d = dq * 4 + c;
      int voff = d * 512 + ((s * 2) ^ ((d & 7) << 4));
      *(unsigned short*)((char*)Vt + voff) = f2bf(vv[c]);
    }
  }
  const float4* asrc = (const float4*)(af + head * 4096);
  for (int i = tid; i < 1024; i += 256) {
    float4 a4 = asrc[i];
    int f = i >> 4, gq = (i & 15) << 2;
    ushort4 a4b = make_ushort4(f2bf(a4.x), f2bf(a4.y), f2bf(a4.z), f2bf(a4.w));
    *(ushort4*)&afl[f * 66 + gq] = a4b;
  }
  __syncthreads();

  const int w = tid >> 6, lane = tid & 63;
  const int lr = lane & 15, lg = lane >> 4;
  const int tw = t0 + w * 16;

  bf16x8 aq[2];
  {
    const float* qrow = qg + head * 16384 + (tw + lr) * 64 + lg * 8;
#pragma unroll
    for (int kc = 0; kc < 2; ++kc) {
      float4 q0 = *(const float4*)(qrow + kc * 32);
      float4 q1 = *(const float4*)(qrow + kc * 32 + 4);
      bf16x8 a;
      a[0] = (short)f2bf(q0.x); a[1] = (short)f2bf(q0.y);
      a[2] = (short)f2bf(q0.z); a[3] = (short)f2bf(q0.w);
      a[4] = (short)f2bf(q1.x); a[5] = (short)f2bf(q1.y);
      a[6] = (short)f2bf(q1.z); a[7] = (short)f2bf(q1.w);
      aq[kc] = a;
    }
  }

  f32x4 S[16];
#pragma unroll
  for (int nt = 0; nt < 16; ++nt) {
    f32x4 accv = {0.f, 0.f, 0.f, 0.f};
#pragma unroll
    for (int kc = 0; kc < 2; ++kc) {
      int srow = nt * 16 + lr;
      int d0 = kc * 32 + lg * 8;
      int off = srow * 128 + ((d0 * 2) ^ ((srow & 7) << 4));
      bf16x8 bk = *(bf16x8*)((char*)Ks + off);
      accv = __builtin_amdgcn_mfma_f32_16x16x32_bf16(aq[kc], bk, accv, 0, 0, 0);
    }
    S[nt] = accv;
  }

  float inv[4], mrow[4];
#pragma unroll
  for (int j = 0; j < 4; ++j) {
    float m = -1e30f;
#pragma unroll
    for (int nt = 0; nt < 16; ++nt) m = fmaxf(m, S[nt][j]);
#pragma unroll
    for (int mask = 1; mask < 16; mask <<= 1) m = fmaxf(m, __shfl_xor(m, mask));
    mrow[j] = m;
  }
#pragma unroll
  for (int j = 0; j < 4; ++j) {
    float rs = 0.f;
#pragma unroll
    for (int nt = 0; nt < 16; ++nt) {
      float e = __expf((S[nt][j] - mrow[j]) * SCALE);
      S[nt][j] = e;
      rs += e;
    }
#pragma unroll
    for (int mask = 1; mask < 16; mask <<= 1) rs += __shfl_xor(rs, mask);
    inv[j] = 1.0f / rs;
  }

  {
    const float wv = weight[0];
    const float gate = 1.0f / (1.0f + __expf(-fgate[0]));
    const float* amh = att_map + (size_t)head * 65536;
#pragma unroll
    for (int j = 0; j < 4; ++j) {
      const int t = tw + lg * 4 + j;
      float srcf = fmaxf((t + 0.5f) * (129.0f / 256.0f) - 0.5f, 0.0f);
      int f0r = (int)srcf;
      float wf = srcf - (float)f0r;
      int f1r = f0r + 1;
      if (f1r > 128) f1r = 128;
      const bool v0 = (f0r < 64), v1 = (f1r < 64);
#pragma unroll
      for (int nt = 0; nt < 16; ++nt) {
        const int s = nt * 16 + lr;
        float am = amh[t * 256 + s];
        float srcg = fmaxf((s + 0.5f) * 0.25f - 0.5f, 0.0f);
        int g0 = (int)srcg;
        float wc = srcg - (float)g0;
        int g1 = g0 + 1;
        if (g1 > 63) g1 = 63;
        float fr = 0.f;
        if (v0)
          fr += (1.0f - wf) *
                (bf2f(afl[f0r * 66 + g0]) * (1.0f - wc) + bf2f(afl[f0r * 66 + g1]) * wc);
        if (v1)
          fr += wf *
                (bf2f(afl[f1r * 66 + g0]) * (1.0f - wc) + bf2f(afl[f1r * 66 + g1]) * wc);
        float pt = S[nt][j] * inv[j];
        S[nt][j] = wv * (gate * fr + (1.0f - gate) * pt) + (1.0f - wv) * am;
      }
    }
  }

  f32x4 O[4];
#pragma unroll
  for (int dt = 0; dt < 4; ++dt) O[dt] = (f32x4){0.f, 0.f, 0.f, 0.f};
  unsigned short* psc = Psc[w];
#pragma unroll
  for (int sb = 0; sb < 8; ++sb) {
#pragma unroll
    for (int half = 0; half < 2; ++half) {
      const int nt = sb * 2 + half;
#pragma unroll
      for (int j = 0; j < 4; ++j) {
        psc[(lg * 4 + j) * 40 + half * 16 + lr] = f2bf(S[nt][j]);
      }
    }
    bf16x8 pa = *(bf16x8*)&psc[lr * 40 + lg * 8];
#pragma unroll
    for (int dt = 0; dt < 4; ++dt) {
      int d = dt * 16 + lr;
      int s0 = sb * 32 + lg * 8;
      int off = d * 512 + ((s0 * 2) ^ ((d & 7) << 4));
      bf16x8 bv = *(bf16x8*)((char*)Vt + off);
      O[dt] = __builtin_amdgcn_mfma_f32_16x16x32_bf16(pa, bv, O[dt], 0, 0, 0);
    }
  }

#pragma unroll
  for (int j = 0; j < 4; ++j) {
    const int t = tw + lg * 4 + j;
    float* orow = out_perm + ((size_t)((b * 256 + t) * 17 + jj)) * 512 + h * 64;
#pragma unroll
    for (int dt = 0; dt < 4; ++dt) {
      orow[dt * 16 + lr] = O[dt][j];
    }
  }
}

// ---------------- K4: d_out = out_perm @ w_proj + b_proj (split-bf16 MFMA) --------
// blockIdx.x = n-tile (512/128 = 4), blockIdx.y = m-tile (136).
__global__ __launch_bounds__(256, 2) void proj_gemm(
    const float* __restrict__ A, const float* __restrict__ wp,
    const float* __restrict__ bias, float* __restrict__ out) {
  __shared__ __attribute__((aligned(16))) unsigned short Wl[2][128 * 64];
  __shared__ __attribute__((aligned(16))) unsigned short Xl[2][128 * 64];

  const int tid = threadIdx.x;
  const int bx = blockIdx.x;
  const int by = blockIdx.y;
  const int wid = tid >> 6, lane = tid & 63;
  const int lr = lane & 15, lg = lane >> 4;
  const int wr = wid >> 1, wc = wid & 1;

  f32x4 acc[4][4];
#pragma unroll
  for (int nt = 0; nt < 4; ++nt)
#pragma unroll
    for (int mt = 0; mt < 4; ++mt) acc[nt][mt] = (f32x4){0.f, 0.f, 0.f, 0.f};

  for (int k0 = 0; k0 < 512; k0 += 64) {
#pragma unroll
    for (int i = 0; i < 8; ++i) {
      const int f4i = tid + 256 * i;
      const int row = f4i >> 4, cq = f4i & 15;
      float4 v4 = *(const float4*)(A + (size_t)(by * 128 + row) * 512 + k0 + cq * 4);
      ushort4 hi, lo;
      hi.x = f2bf(v4.x); lo.x = f2bf(v4.x - bf2f(hi.x));
      hi.y = f2bf(v4.y); lo.y = f2bf(v4.y - bf2f(hi.y));
      hi.z = f2bf(v4.z); lo.z = f2bf(v4.z - bf2f(hi.z));
      hi.w = f2bf(v4.w); lo.w = f2bf(v4.w - bf2f(hi.w));
      const int byo = row * 128 + ((cq * 8) ^ ((row & 7) << 4));
      *(ushort4*)((char*)Xl[0] + byo) = hi;
      *(ushort4*)((char*)Xl[1] + byo) = lo;
    }
#pragma unroll
    for (int i = 0; i < 8; ++i) {
      const int f4i = tid + 256 * i;
      const int kr = f4i >> 5, nq = f4i & 31;
      float4 v4 = *(const float4*)(wp + (size_t)(k0 + kr) * 512 + bx * 128 + nq * 4);
      float vv[4] = {v4.x, v4.y, v4.z, v4.w};
#pragma unroll
      for (int c = 0; c < 4; ++c) {
        const int n = nq * 4 + c;
        unsigned short hi = f2bf(vv[c]);
        unsigned short lo = f2bf(vv[c] - bf2f(hi));
        const int byo = n * 128 + ((kr * 2) ^ ((n & 7) << 4));
        *(unsigned short*)((char*)Wl[0] + byo) = hi;
        *(unsigned short*)((char*)Wl[1] + byo) = lo;
      }
    }
    __syncthreads();

#pragma unroll
    for (int kh = 0; kh < 2; ++kh) {
      const int kbase = kh * 32 + lg * 8;
      bf16x8 Ah[4], Al[4], Bh[4], Bl[4];
#pragma unroll
      for (int nt = 0; nt < 4; ++nt) {
        const int n = wr * 64 + nt * 16 + lr;
        const int byo = n * 128 + ((kbase * 2) ^ ((n & 7) << 4));
        Ah[nt] = *(bf16x8*)((char*)Wl[0] + byo);
        Al[nt] = *(bf16x8*)((char*)Wl[1] + byo);
      }
#pragma unroll
      for (int mt = 0; mt < 4; ++mt) {
        const int m = wc * 64 + mt * 16 + lr;
        const int byo = m * 128 + ((kbase * 2) ^ ((m & 7) << 4));
        Bh[mt] = *(bf16x8*)((char*)Xl[0] + byo);
        Bl[mt] = *(bf16x8*)((char*)Xl[1] + byo);
      }
#pragma unroll
      for (int nt = 0; nt < 4; ++nt)
#pragma unroll
        for (int mt = 0; mt < 4; ++mt) {
          acc[nt][mt] = __builtin_amdgcn_mfma_f32_16x16x32_bf16(Ah[nt], Bh[mt], acc[nt][mt], 0, 0, 0);
          acc[nt][mt] = __builtin_amdgcn_mfma_f32_16x16x32_bf16(Ah[nt], Bl[mt], acc[nt][mt], 0, 0, 0);
          acc[nt][mt] = __builtin_amdgcn_mfma_f32_16x16x32_bf16(Al[nt], Bh[mt], acc[nt][mt], 0, 0, 0);
        }
    }
    __syncthreads();
  }

#pragma unroll
  for (int mt = 0; mt < 4; ++mt) {
    const int m = by * 128 + wc * 64 + mt * 16 + lr;
#pragma unroll
    for (int nt = 0; nt < 4; ++nt) {
      const int n = bx * 128 + wr * 64 + nt * 16 + lg * 4;
      float4 bi = *(const float4*)&bias[n];
      *(float4*)&out[(size_t)m * 512 + n] =
          make_float4(acc[nt][mt][0] + bi.x, acc[nt][mt][1] + bi.y,
                      acc[nt][mt][2] + bi.z, acc[nt][mt][3] + bi.w);
    }
  }
}

extern "C" void kernel_launch(void* const* d_in, const int* in_sizes, int n_in,
                              void* d_out, int out_size, void* d_ws, size_t ws_size,
                              hipStream_t stream) {
  (void)in_sizes; (void)n_in; (void)out_size; (void)ws_size;
  const float* x = (const float*)d_in[0];
  const float* att_map = (const float*)d_in[1];
  const float* weight = (const float*)d_in[2];
  const float* w_qkv = (const float*)d_in[3];
  const float* w_proj = (const float*)d_in[4];
  const float* b_proj = (const float*)d_in[5];
  const float* fgate = (const float*)d_in[6];
  float* out = (float*)d_out;

  char* ws = (char*)d_ws;
  const size_t HB = 35651584;  // 544*16384 f32 bytes
  float* qb = (float*)(ws);
  float* kb = (float*)(ws + HB);
  float* vb = (float*)(ws + 2 * HB);
  float* af = (float*)(ws + 3 * HB);
  float* out_perm = (float*)(ws + 3 * HB + 8912896);

  qkv_gemm<<<dim3(12, 136), 256, 0, stream>>>(x, w_qkv, qb, kb, vb);
  freq_kernel<<<544, 256, 0, stream>>>(qb, kb, af);
  attn_kernel<<<dim3(4, 544), 256, 0, stream>>>(qb, kb, vb, af, att_map, weight,
                                                fgate, out_perm);
  proj_gemm<<<dim3(4, 136), 256, 0, stream>>>(out_perm, w_proj, b_proj, out);
}

// Round 6
// 589.429 us; speedup vs baseline: 2.7338x; 1.1610x over previous
//
#include <hip/hip_runtime.h>
#include <hip/hip_bf16.h>

// FrequencyAwareSumAttention — round 6: kill the 100M LDS bank conflicts in the
// split-bf16 MFMA GEMMs (K1, K4): 144-B row stride (no XOR), ushort8 W staging.
// K2 (MFMA DFT) and K3 (MFMA attention) unchanged.

#define SCALE 0.125f

typedef __attribute__((ext_vector_type(4))) float f32x4;
typedef __attribute__((ext_vector_type(8))) short bf16x8;
typedef __attribute__((ext_vector_type(8))) unsigned short u16x8;

__device__ __forceinline__ float bf2f(unsigned short u) {
  return __uint_as_float(((unsigned int)u) << 16);
}
__device__ __forceinline__ unsigned short f2bf(float f) {
  unsigned int u = __float_as_uint(f);
  u += 0x7FFFu + ((u >> 16) & 1u);
  return (unsigned short)(u >> 16);
}

// ---------------- K1: qkv = x @ w_qkv (split-bf16 MFMA), scatter fp32 head-major ----
// A-side = w_qkv columns (n), B-side = x rows (m).
// blockIdx.x = n-tile (1536/128 = 12), blockIdx.y = m-tile (17408/128 = 136).
// LDS tiles: [row 128][k 72] ushorts (144-B stride) — conflict-free staging + frags.
#define LSTR 72
__global__ __launch_bounds__(256, 2) void qkv_gemm(
    const float* __restrict__ x, const float* __restrict__ wq,
    float* __restrict__ q, float* __restrict__ k, float* __restrict__ v) {
  __shared__ __attribute__((aligned(16))) unsigned short Wl[2][128 * LSTR];
  __shared__ __attribute__((aligned(16))) unsigned short Xl[2][128 * LSTR];

  const int tid = threadIdx.x;
  const int bx = blockIdx.x;
  const int by = blockIdx.y;
  const int wid = tid >> 6, lane = tid & 63;
  const int lr = lane & 15, lg = lane >> 4;
  const int wr = wid >> 1, wc = wid & 1;  // n-half, m-half

  f32x4 acc[4][4];
#pragma unroll
  for (int nt = 0; nt < 4; ++nt)
#pragma unroll
    for (int mt = 0; mt < 4; ++mt) acc[nt][mt] = (f32x4){0.f, 0.f, 0.f, 0.f};

  for (int k0 = 0; k0 < 512; k0 += 64) {
    // ---- stage X: thread owns (row, kg): 2 float4 loads -> ushort8 hi/lo ----
#pragma unroll
    for (int it = 0; it < 4; ++it) {
      const int f = tid + 256 * it;
      const int kg = f & 7, row = f >> 3;  // row 0..127, kg 0..7
      const float* src = x + (size_t)(by * 128 + row) * 512 + k0 + kg * 8;
      float4 a4 = *(const float4*)(src);
      float4 b4 = *(const float4*)(src + 4);
      float vv[8] = {a4.x, a4.y, a4.z, a4.w, b4.x, b4.y, b4.z, b4.w};
      u16x8 hi, lo;
#pragma unroll
      for (int e = 0; e < 8; ++e) {
        unsigned short h = f2bf(vv[e]);
        hi[e] = h;
        lo[e] = f2bf(vv[e] - bf2f(h));
      }
      const int base = row * LSTR + kg * 8;
      *(u16x8*)&Xl[0][base] = hi;
      *(u16x8*)&Xl[1][base] = lo;
    }
    // ---- stage W^T: thread owns (n, kg): 8 k-strided scalars -> ushort8 hi/lo ----
#pragma unroll
    for (int it = 0; it < 4; ++it) {
      const int f = tid + 256 * it;
      const int n = f & 127, kg = f >> 7;  // n 0..127, kg 0..7
      const float* src = wq + (size_t)(k0 + kg * 8) * 1536 + bx * 128 + n;
      u16x8 hi, lo;
#pragma unroll
      for (int e = 0; e < 8; ++e) {
        float vv = src[(size_t)e * 1536];
        unsigned short h = f2bf(vv);
        hi[e] = h;
        lo[e] = f2bf(vv - bf2f(h));
      }
      const int base = n * LSTR + kg * 8;
      *(u16x8*)&Wl[0][base] = hi;
      *(u16x8*)&Wl[1][base] = lo;
    }
    __syncthreads();

#pragma unroll
    for (int kh = 0; kh < 2; ++kh) {
      const int kbase = kh * 32 + lg * 8;
      bf16x8 Ah[4], Al[4], Bh[4], Bl[4];
#pragma unroll
      for (int nt = 0; nt < 4; ++nt) {
        const int n = wr * 64 + nt * 16 + lr;
        Ah[nt] = *(bf16x8*)&Wl[0][n * LSTR + kbase];
        Al[nt] = *(bf16x8*)&Wl[1][n * LSTR + kbase];
      }
#pragma unroll
      for (int mt = 0; mt < 4; ++mt) {
        const int m = wc * 64 + mt * 16 + lr;
        Bh[mt] = *(bf16x8*)&Xl[0][m * LSTR + kbase];
        Bl[mt] = *(bf16x8*)&Xl[1][m * LSTR + kbase];
      }
#pragma unroll
      for (int nt = 0; nt < 4; ++nt)
#pragma unroll
        for (int mt = 0; mt < 4; ++mt) {
          acc[nt][mt] = __builtin_amdgcn_mfma_f32_16x16x32_bf16(Ah[nt], Bh[mt], acc[nt][mt], 0, 0, 0);
          acc[nt][mt] = __builtin_amdgcn_mfma_f32_16x16x32_bf16(Ah[nt], Bl[mt], acc[nt][mt], 0, 0, 0);
          acc[nt][mt] = __builtin_amdgcn_mfma_f32_16x16x32_bf16(Al[nt], Bh[mt], acc[nt][mt], 0, 0, 0);
        }
    }
    __syncthreads();
  }

  // epilogue: D col = m (x-row), D reg j -> n+j (w-col). float4 per acc.
#pragma unroll
  for (int mt = 0; mt < 4; ++mt) {
    const int m = by * 128 + wc * 64 + mt * 16 + lr;
    const int jj = m % 17;
    const int bt = m / 17;
    const int t = bt & 255;
    const int b = bt >> 8;
#pragma unroll
    for (int nt = 0; nt < 4; ++nt) {
      const int c = bx * 128 + wr * 64 + nt * 16 + lg * 4;
      const int qi = c >> 9;
      const int h = (c >> 6) & 7;
      const int dd = c & 63;
      float* dst = (qi == 0) ? q : (qi == 1) ? k : v;
      *(float4*)&dst[((size_t)((b * 8 + h) * 17 + jj)) * 16384 + t * 64 + dd] =
          make_float4(acc[nt][mt][0], acc[nt][mt][1], acc[nt][mt][2], acc[nt][mt][3]);
    }
  }
}

// ---------------- K2: split-precision MFMA DFT + af GEMM + freq softmax ----------------
__global__ __launch_bounds__(256) void freq_kernel(
    const float* __restrict__ qg, const float* __restrict__ kg,
    float* __restrict__ af_out) {
  __shared__ __attribute__((aligned(16))) unsigned short qT[2][64 * 256];
  __shared__ __attribute__((aligned(16))) unsigned short QF[4][64 * 64];
  __shared__ __attribute__((aligned(16))) unsigned short KF[4][64 * 64];

  const int tid = threadIdx.x;
  const int head = blockIdx.x;
  const int w = tid >> 6, lane = tid & 63;
  const int lr = lane & 15, lg = lane >> 4;
  const int f0 = w << 4;

  bf16x8 Ech[8], Ecl[8], Esh[8], Esl[8];
  {
    const int f = f0 + lr;
#pragma unroll
    for (int kb = 0; kb < 8; ++kb) {
      bf16x8 ch, cl, sh, sl;
#pragma unroll
      for (int i = 0; i < 8; ++i) {
        int t = kb * 32 + lg * 8 + i;
        int idx = (f * t) & 255;
        float s, c;
        __sincosf((float)idx * 0.02454369260617026f, &s, &c);
        unsigned short chh = f2bf(c);
        unsigned short shh = f2bf(s);
        ch[i] = (short)chh;
        cl[i] = (short)f2bf(c - bf2f(chh));
        sh[i] = (short)shh;
        sl[i] = (short)f2bf(s - bf2f(shh));
      }
      Ech[kb] = ch; Ecl[kb] = cl; Esh[kb] = sh; Esl[kb] = sl;
    }
  }

  for (int pass = 0; pass < 2; ++pass) {
    const float* src = pass ? kg : qg;
    __syncthreads();
    const float4* s4 = (const float4*)(src + head * 16384);
    for (int i = tid; i < 4096; i += 256) {
      int t = i >> 4, dq = i & 15;
      float4 v4 = s4[i];
      float vv[4] = {v4.x, v4.y, v4.z, v4.w};
#pragma unroll
      for (int c = 0; c < 4; ++c) {
        int d = dq * 4 + c;
        unsigned short hi = f2bf(vv[c]);
        unsigned short lo = f2bf(vv[c] - bf2f(hi));
        int byo = d * 512 + ((t * 2) ^ ((d & 31) << 4));
        *(unsigned short*)((char*)qT[0] + byo) = hi;
        *(unsigned short*)((char*)qT[1] + byo) = lo;
      }
    }
    __syncthreads();

    f32x4 ar[4], ai[4];
#pragma unroll
    for (int nt = 0; nt < 4; ++nt) {
      ar[nt] = (f32x4){0.f, 0.f, 0.f, 0.f};
      ai[nt] = (f32x4){0.f, 0.f, 0.f, 0.f};
    }
#pragma unroll
    for (int kb = 0; kb < 8; ++kb) {
#pragma unroll
      for (int nt = 0; nt < 4; ++nt) {
        const int d = nt * 16 + lr;
        const int byo = d * 512 + ((kb * 64 + lg * 16) ^ ((d & 31) << 4));
        bf16x8 bh = *(bf16x8*)((char*)qT[0] + byo);
        bf16x8 bl = *(bf16x8*)((char*)qT[1] + byo);
        ar[nt] = __builtin_amdgcn_mfma_f32_16x16x32_bf16(Ech[kb], bh, ar[nt], 0, 0, 0);
        ar[nt] = __builtin_amdgcn_mfma_f32_16x16x32_bf16(Ech[kb], bl, ar[nt], 0, 0, 0);
        ar[nt] = __builtin_amdgcn_mfma_f32_16x16x32_bf16(Ecl[kb], bh, ar[nt], 0, 0, 0);
        ai[nt] = __builtin_amdgcn_mfma_f32_16x16x32_bf16(Esh[kb], bh, ai[nt], 0, 0, 0);
        ai[nt] = __builtin_amdgcn_mfma_f32_16x16x32_bf16(Esh[kb], bl, ai[nt], 0, 0, 0);
        ai[nt] = __builtin_amdgcn_mfma_f32_16x16x32_bf16(Esl[kb], bh, ai[nt], 0, 0, 0);
      }
    }
    unsigned short(*DST)[64 * 64] = pass ? KF : QF;
#pragma unroll
    for (int nt = 0; nt < 4; ++nt) {
#pragma unroll
      for (int j = 0; j < 4; ++j) {
        const int f = f0 + lg * 4 + j;
        const int d = nt * 16 + lr;
        const int byo = f * 128 + ((d * 2) ^ ((f & 7) << 4));
        float vr = ar[nt][j], vi = ai[nt][j];
        unsigned short rh = f2bf(vr);
        unsigned short ih = f2bf(vi);
        *(unsigned short*)((char*)DST[0] + byo) = rh;
        *(unsigned short*)((char*)DST[1] + byo) = f2bf(vr - bf2f(rh));
        *(unsigned short*)((char*)DST[2] + byo) = ih;
        *(unsigned short*)((char*)DST[3] + byo) = f2bf(vi - bf2f(ih));
      }
    }
  }
  __syncthreads();

  f32x4 acc[4];
#pragma unroll
  for (int nt = 0; nt < 4; ++nt) acc[nt] = (f32x4){0.f, 0.f, 0.f, 0.f};
#pragma unroll
  for (int kb = 0; kb < 2; ++kb) {
    const int fA = f0 + lr;
    const int abyo = fA * 128 + ((kb * 64 + lg * 16) ^ ((fA & 7) << 4));
    bf16x8 arh = *(bf16x8*)((char*)QF[0] + abyo);
    bf16x8 arl = *(bf16x8*)((char*)QF[1] + abyo);
    bf16x8 aih = *(bf16x8*)((char*)QF[2] + abyo);
    bf16x8 ail = *(bf16x8*)((char*)QF[3] + abyo);
#pragma unroll
    for (int nt = 0; nt < 4; ++nt) {
      const int g = nt * 16 + lr;
      const int bbyo = g * 128 + ((kb * 64 + lg * 16) ^ ((g & 7) << 4));
      bf16x8 brh = *(bf16x8*)((char*)KF[0] + bbyo);
      bf16x8 brl = *(bf16x8*)((char*)KF[1] + bbyo);
      bf16x8 bih = *(bf16x8*)((char*)KF[2] + bbyo);
      bf16x8 bil = *(bf16x8*)((char*)KF[3] + bbyo);
      acc[nt] = __builtin_amdgcn_mfma_f32_16x16x32_bf16(arh, brh, acc[nt], 0, 0, 0);
      acc[nt] = __builtin_amdgcn_mfma_f32_16x16x32_bf16(arh, brl, acc[nt], 0, 0, 0);
      acc[nt] = __builtin_amdgcn_mfma_f32_16x16x32_bf16(arl, brh, acc[nt], 0, 0, 0);
      acc[nt] = __builtin_amdgcn_mfma_f32_16x16x32_bf16(aih, bih, acc[nt], 0, 0, 0);
      acc[nt] = __builtin_amdgcn_mfma_f32_16x16x32_bf16(aih, bil, acc[nt], 0, 0, 0);
      acc[nt] = __builtin_amdgcn_mfma_f32_16x16x32_bf16(ail, bih, acc[nt], 0, 0, 0);
    }
  }

  float* outh = af_out + head * 4096;
#pragma unroll
  for (int j = 0; j < 4; ++j) {
    float m = fmaxf(fmaxf(acc[0][j], acc[1][j]), fmaxf(acc[2][j], acc[3][j]));
#pragma unroll
    for (int mask = 1; mask < 16; mask <<= 1) m = fmaxf(m, __shfl_xor(m, mask));
    float e[4];
    float rs = 0.f;
#pragma unroll
    for (int nt = 0; nt < 4; ++nt) {
      e[nt] = __expf((acc[nt][j] - m) * SCALE);
      rs += e[nt];
    }
#pragma unroll
    for (int mask = 1; mask < 16; mask <<= 1) rs += __shfl_xor(rs, mask);
    const float inv = 1.0f / rs;
    const int f = f0 + lg * 4 + j;
#pragma unroll
    for (int nt = 0; nt < 4; ++nt) outh[f * 64 + nt * 16 + lr] = e[nt] * inv;
  }
}

// ---------------- K3: MFMA attention (unchanged, verified) ----------------
__global__ __launch_bounds__(256) void attn_kernel(
    const float* __restrict__ qg, const float* __restrict__ kg,
    const float* __restrict__ vg, const float* __restrict__ af,
    const float* __restrict__ att_map, const float* __restrict__ weight,
    const float* __restrict__ fgate, float* __restrict__ out_perm) {
  __shared__ unsigned short Ks[256 * 64];
  __shared__ unsigned short Vt[64 * 256];
  __shared__ unsigned short afl[64 * 66];
  __shared__ unsigned short Psc[4][16 * 40];

  const int tid = threadIdx.x;
  const int t0 = blockIdx.x << 6;
  const int head = blockIdx.y;
  const int jj = head % 17;
  const int hb = head / 17;
  const int h = hb & 7;
  const int b = hb >> 3;

  const float4* ksrc = (const float4*)(kg + head * 16384);
  const float4* vsrc = (const float4*)(vg + head * 16384);
  for (int i = tid; i < 4096; i += 256) {
    int s = i >> 4, dq = i & 15;
    float4 kf = ksrc[i];
    ushort4 k4 = make_ushort4(f2bf(kf.x), f2bf(kf.y), f2bf(kf.z), f2bf(kf.w));
    int koff = s * 128 + ((dq * 8) ^ ((s & 7) << 4));
    *(ushort4*)((char*)Ks + koff) = k4;
    float4 vf = vsrc[i];
    float vv[4] = {vf.x, vf.y, vf.z, vf.w};
#pragma unroll
    for (int c = 0; c < 4; ++c) {
      int d = dq * 4 + c;
      int voff = d * 512 + ((s * 2) ^ ((d & 7) << 4));
      *(unsigned short*)((char*)Vt + voff) = f2bf(vv[c]);
    }
  }
  const float4* asrc = (const float4*)(af + head * 4096);
  for (int i = tid; i < 1024; i += 256) {
    float4 a4 = asrc[i];
    int f = i >> 4, gq = (i & 15) << 2;
    ushort4 a4b = make_ushort4(f2bf(a4.x), f2bf(a4.y), f2bf(a4.z), f2bf(a4.w));
    *(ushort4*)&afl[f * 66 + gq] = a4b;
  }
  __syncthreads();

  const int w = tid >> 6, lane = tid & 63;
  const int lr = lane & 15, lg = lane >> 4;
  const int tw = t0 + w * 16;

  bf16x8 aq[2];
  {
    const float* qrow = qg + head * 16384 + (tw + lr) * 64 + lg * 8;
#pragma unroll
    for (int kc = 0; kc < 2; ++kc) {
      float4 q0 = *(const float4*)(qrow + kc * 32);
      float4 q1 = *(const float4*)(qrow + kc * 32 + 4);
      bf16x8 a;
      a[0] = (short)f2bf(q0.x); a[1] = (short)f2bf(q0.y);
      a[2] = (short)f2bf(q0.z); a[3] = (short)f2bf(q0.w);
      a[4] = (short)f2bf(q1.x); a[5] = (short)f2bf(q1.y);
      a[6] = (short)f2bf(q1.z); a[7] = (short)f2bf(q1.w);
      aq[kc] = a;
    }
  }

  f32x4 S[16];
#pragma unroll
  for (int nt = 0; nt < 16; ++nt) {
    f32x4 accv = {0.f, 0.f, 0.f, 0.f};
#pragma unroll
    for (int kc = 0; kc < 2; ++kc) {
      int srow = nt * 16 + lr;
      int d0 = kc * 32 + lg * 8;
      int off = srow * 128 + ((d0 * 2) ^ ((srow & 7) << 4));
      bf16x8 bk = *(bf16x8*)((char*)Ks + off);
      accv = __builtin_amdgcn_mfma_f32_16x16x32_bf16(aq[kc], bk, accv, 0, 0, 0);
    }
    S[nt] = accv;
  }

  float inv[4], mrow[4];
#pragma unroll
  for (int j = 0; j < 4; ++j) {
    float m = -1e30f;
#pragma unroll
    for (int nt = 0; nt < 16; ++nt) m = fmaxf(m, S[nt][j]);
#pragma unroll
    for (int mask = 1; mask < 16; mask <<= 1) m = fmaxf(m, __shfl_xor(m, mask));
    mrow[j] = m;
  }
#pragma unroll
  for (int j = 0; j < 4; ++j) {
    float rs = 0.f;
#pragma unroll
    for (int nt = 0; nt < 16; ++nt) {
      float e = __expf((S[nt][j] - mrow[j]) * SCALE);
      S[nt][j] = e;
      rs += e;
    }
#pragma unroll
    for (int mask = 1; mask < 16; mask <<= 1) rs += __shfl_xor(rs, mask);
    inv[j] = 1.0f / rs;
  }

  {
    const float wv = weight[0];
    const float gate = 1.0f / (1.0f + __expf(-fgate[0]));
    const float* amh = att_map + (size_t)head * 65536;
#pragma unroll
    for (int j = 0; j < 4; ++j) {
      const int t = tw + lg * 4 + j;
      float srcf = fmaxf((t + 0.5f) * (129.0f / 256.0f) - 0.5f, 0.0f);
      int f0r = (int)srcf;
      float wf = srcf - (float)f0r;
      int f1r = f0r + 1;
      if (f1r > 128) f1r = 128;
      const bool v0 = (f0r < 64), v1 = (f1r < 64);
#pragma unroll
      for (int nt = 0; nt < 16; ++nt) {
        const int s = nt * 16 + lr;
        float am = amh[t * 256 + s];
        float srcg = fmaxf((s + 0.5f) * 0.25f - 0.5f, 0.0f);
        int g0 = (int)srcg;
        float wc = srcg - (float)g0;
        int g1 = g0 + 1;
        if (g1 > 63) g1 = 63;
        float fr = 0.f;
        if (v0)
          fr += (1.0f - wf) *
                (bf2f(afl[f0r * 66 + g0]) * (1.0f - wc) + bf2f(afl[f0r * 66 + g1]) * wc);
        if (v1)
          fr += wf *
                (bf2f(afl[f1r * 66 + g0]) * (1.0f - wc) + bf2f(afl[f1r * 66 + g1]) * wc);
        float pt = S[nt][j] * inv[j];
        S[nt][j] = wv * (gate * fr + (1.0f - gate) * pt) + (1.0f - wv) * am;
      }
    }
  }

  f32x4 O[4];
#pragma unroll
  for (int dt = 0; dt < 4; ++dt) O[dt] = (f32x4){0.f, 0.f, 0.f, 0.f};
  unsigned short* psc = Psc[w];
#pragma unroll
  for (int sb = 0; sb < 8; ++sb) {
#pragma unroll
    for (int half = 0; half < 2; ++half) {
      const int nt = sb * 2 + half;
#pragma unroll
      for (int j = 0; j < 4; ++j) {
        psc[(lg * 4 + j) * 40 + half * 16 + lr] = f2bf(S[nt][j]);
      }
    }
    bf16x8 pa = *(bf16x8*)&psc[lr * 40 + lg * 8];
#pragma unroll
    for (int dt = 0; dt < 4; ++dt) {
      int d = dt * 16 + lr;
      int s0 = sb * 32 + lg * 8;
      int off = d * 512 + ((s0 * 2) ^ ((d & 7) << 4));
      bf16x8 bv = *(bf16x8*)((char*)Vt + off);
      O[dt] = __builtin_amdgcn_mfma_f32_16x16x32_bf16(pa, bv, O[dt], 0, 0, 0);
    }
  }

#pragma unroll
  for (int j = 0; j < 4; ++j) {
    const int t = tw + lg * 4 + j;
    float* orow = out_perm + ((size_t)((b * 256 + t) * 17 + jj)) * 512 + h * 64;
#pragma unroll
    for (int dt = 0; dt < 4; ++dt) {
      orow[dt * 16 + lr] = O[dt][j];
    }
  }
}

// ---------------- K4: d_out = out_perm @ w_proj + b_proj (split-bf16 MFMA) --------
// blockIdx.x = n-tile (512/128 = 4), blockIdx.y = m-tile (136).
__global__ __launch_bounds__(256, 2) void proj_gemm(
    const float* __restrict__ A, const float* __restrict__ wp,
    const float* __restrict__ bias, float* __restrict__ out) {
  __shared__ __attribute__((aligned(16))) unsigned short Wl[2][128 * LSTR];
  __shared__ __attribute__((aligned(16))) unsigned short Xl[2][128 * LSTR];

  const int tid = threadIdx.x;
  const int bx = blockIdx.x;
  const int by = blockIdx.y;
  const int wid = tid >> 6, lane = tid & 63;
  const int lr = lane & 15, lg = lane >> 4;
  const int wr = wid >> 1, wc = wid & 1;

  f32x4 acc[4][4];
#pragma unroll
  for (int nt = 0; nt < 4; ++nt)
#pragma unroll
    for (int mt = 0; mt < 4; ++mt) acc[nt][mt] = (f32x4){0.f, 0.f, 0.f, 0.f};

  for (int k0 = 0; k0 < 512; k0 += 64) {
#pragma unroll
    for (int it = 0; it < 4; ++it) {
      const int f = tid + 256 * it;
      const int kg = f & 7, row = f >> 3;
      const float* src = A + (size_t)(by * 128 + row) * 512 + k0 + kg * 8;
      float4 a4 = *(const float4*)(src);
      float4 b4 = *(const float4*)(src + 4);
      float vv[8] = {a4.x, a4.y, a4.z, a4.w, b4.x, b4.y, b4.z, b4.w};
      u16x8 hi, lo;
#pragma unroll
      for (int e = 0; e < 8; ++e) {
        unsigned short h = f2bf(vv[e]);
        hi[e] = h;
        lo[e] = f2bf(vv[e] - bf2f(h));
      }
      const int base = row * LSTR + kg * 8;
      *(u16x8*)&Xl[0][base] = hi;
      *(u16x8*)&Xl[1][base] = lo;
    }
#pragma unroll
    for (int it = 0; it < 4; ++it) {
      const int f = tid + 256 * it;
      const int n = f & 127, kg = f >> 7;
      const float* src = wp + (size_t)(k0 + kg * 8) * 512 + bx * 128 + n;
      u16x8 hi, lo;
#pragma unroll
      for (int e = 0; e < 8; ++e) {
        float vv = src[(size_t)e * 512];
        unsigned short h = f2bf(vv);
        hi[e] = h;
        lo[e] = f2bf(vv - bf2f(h));
      }
      const int base = n * LSTR + kg * 8;
      *(u16x8*)&Wl[0][base] = hi;
      *(u16x8*)&Wl[1][base] = lo;
    }
    __syncthreads();

#pragma unroll
    for (int kh = 0; kh < 2; ++kh) {
      const int kbase = kh * 32 + lg * 8;
      bf16x8 Ah[4], Al[4], Bh[4], Bl[4];
#pragma unroll
      for (int nt = 0; nt < 4; ++nt) {
        const int n = wr * 64 + nt * 16 + lr;
        Ah[nt] = *(bf16x8*)&Wl[0][n * LSTR + kbase];
        Al[nt] = *(bf16x8*)&Wl[1][n * LSTR + kbase];
      }
#pragma unroll
      for (int mt = 0; mt < 4; ++mt) {
        const int m = wc * 64 + mt * 16 + lr;
        Bh[mt] = *(bf16x8*)&Xl[0][m * LSTR + kbase];
        Bl[mt] = *(bf16x8*)&Xl[1][m * LSTR + kbase];
      }
#pragma unroll
      for (int nt = 0; nt < 4; ++nt)
#pragma unroll
        for (int mt = 0; mt < 4; ++mt) {
          acc[nt][mt] = __builtin_amdgcn_mfma_f32_16x16x32_bf16(Ah[nt], Bh[mt], acc[nt][mt], 0, 0, 0);
          acc[nt][mt] = __builtin_amdgcn_mfma_f32_16x16x32_bf16(Ah[nt], Bl[mt], acc[nt][mt], 0, 0, 0);
          acc[nt][mt] = __builtin_amdgcn_mfma_f32_16x16x32_bf16(Al[nt], Bh[mt], acc[nt][mt], 0, 0, 0);
        }
    }
    __syncthreads();
  }

#pragma unroll
  for (int mt = 0; mt < 4; ++mt) {
    const int m = by * 128 + wc * 64 + mt * 16 + lr;
#pragma unroll
    for (int nt = 0; nt < 4; ++nt) {
      const int n = bx * 128 + wr * 64 + nt * 16 + lg * 4;
      float4 bi = *(const float4*)&bias[n];
      *(float4*)&out[(size_t)m * 512 + n] =
          make_float4(acc[nt][mt][0] + bi.x, acc[nt][mt][1] + bi.y,
                      acc[nt][mt][2] + bi.z, acc[nt][mt][3] + bi.w);
    }
  }
}

extern "C" void kernel_launch(void* const* d_in, const int* in_sizes, int n_in,
                              void* d_out, int out_size, void* d_ws, size_t ws_size,
                              hipStream_t stream) {
  (void)in_sizes; (void)n_in; (void)out_size; (void)ws_size;
  const float* x = (const float*)d_in[0];
  const float* att_map = (const float*)d_in[1];
  const float* weight = (const float*)d_in[2];
  const float* w_qkv = (const float*)d_in[3];
  const float* w_proj = (const float*)d_in[4];
  const float* b_proj = (const float*)d_in[5];
  const float* fgate = (const float*)d_in[6];
  float* out = (float*)d_out;

  char* ws = (char*)d_ws;
  const size_t HB = 35651584;  // 544*16384 f32 bytes
  float* qb = (float*)(ws);
  float* kb = (float*)(ws + HB);
  float* vb = (float*)(ws + 2 * HB);
  float* af = (float*)(ws + 3 * HB);
  float* out_perm = (float*)(ws + 3 * HB + 8912896);

  qkv_gemm<<<dim3(12, 136), 256, 0, stream>>>(x, w_qkv, qb, kb, vb);
  freq_kernel<<<544, 256, 0, stream>>>(qb, kb, af);
  attn_kernel<<<dim3(4, 544), 256, 0, stream>>>(qb, kb, vb, af, att_map, weight,
                                                fgate, out_perm);
  proj_gemm<<<dim3(4, 136), 256, 0, stream>>>(out_perm, w_proj, b_proj, out);
}

// Round 7
// 412.721 us; speedup vs baseline: 3.9043x; 1.4282x over previous
//
#include <hip/hip_runtime.h>
#include <hip/hip_bf16.h>

// FrequencyAwareSumAttention — round 7: pre-converted hi/lo-bf16 operand planes +
// software-prefetched staging for K1/K4 (kill the 40-VMEM+640-VALU staging stall).
// K0a conv_x: x -> xh/xl bf16 planes. K0b conv_wT: w -> [n][k] hi/lo planes.
// K1 qkv split-bf16 MFMA GEMM (prefetch, no conversion in-loop)
// K2 MFMA DFT (unchanged)  K3 MFMA attention (unchanged)
// K4 proj split-bf16 MFMA GEMM (prefetch; A-side inline convert, W-side planes)

#define SCALE 0.125f
#define LSTR 72

typedef __attribute__((ext_vector_type(4))) float f32x4;
typedef __attribute__((ext_vector_type(8))) short bf16x8;
typedef __attribute__((ext_vector_type(8))) unsigned short u16x8;

__device__ __forceinline__ float bf2f(unsigned short u) {
  return __uint_as_float(((unsigned int)u) << 16);
}
__device__ __forceinline__ unsigned short f2bf(float f) {
  unsigned int u = __float_as_uint(f);
  u += 0x7FFFu + ((u >> 16) & 1u);
  return (unsigned short)(u >> 16);
}

// ---------------- K0a: x fp32 -> hi/lo bf16 planes ----------------
__global__ __launch_bounds__(256) void conv_x(
    const float* __restrict__ x, unsigned short* __restrict__ xh,
    unsigned short* __restrict__ xl) {
  const size_t i = ((size_t)blockIdx.x * 256 + threadIdx.x) * 8;
  float4 a = *(const float4*)(x + i);
  float4 b = *(const float4*)(x + i + 4);
  float vv[8] = {a.x, a.y, a.z, a.w, b.x, b.y, b.z, b.w};
  u16x8 hi, lo;
#pragma unroll
  for (int e = 0; e < 8; ++e) {
    unsigned short h = f2bf(vv[e]);
    hi[e] = h;
    lo[e] = f2bf(vv[e] - bf2f(h));
  }
  *(u16x8*)&xh[i] = hi;
  *(u16x8*)&xl[i] = lo;
}

// ---------------- K0b: w [K=512][N] -> transposed [N][512] hi/lo planes ----------
__global__ __launch_bounds__(256) void conv_wT(
    const float* __restrict__ w, unsigned short* __restrict__ th,
    unsigned short* __restrict__ tl, int N) {
  __shared__ float T[64][65];
  const int tid = threadIdx.x;
  const int nt = blockIdx.x * 64, kt = blockIdx.y * 64;
  for (int i = tid; i < 4096; i += 256) {
    const int r = i >> 6, c = i & 63;
    T[r][c] = w[(size_t)(kt + r) * N + nt + c];
  }
  __syncthreads();
  for (int i = tid; i < 4096; i += 256) {
    const int rn = i >> 6, ck = i & 63;
    const float v = T[ck][rn];
    const unsigned short h = f2bf(v);
    const size_t o = (size_t)(nt + rn) * 512 + kt + ck;
    th[o] = h;
    tl[o] = f2bf(v - bf2f(h));
  }
}

// ---------------- K1: qkv = x @ w_qkv (split-bf16 MFMA, prefetched) ----------------
// blockIdx.x = n-tile (12), blockIdx.y = m-tile (136). LDS [row][72] u16, 144-B stride.
__global__ __launch_bounds__(256, 2) void qkv_gemm(
    const unsigned short* __restrict__ xh, const unsigned short* __restrict__ xl,
    const unsigned short* __restrict__ wh, const unsigned short* __restrict__ wl,
    float* __restrict__ q, float* __restrict__ k, float* __restrict__ v) {
  __shared__ __attribute__((aligned(16))) unsigned short Wt[2][128 * LSTR];
  __shared__ __attribute__((aligned(16))) unsigned short Xt[2][128 * LSTR];

  const int tid = threadIdx.x;
  const int bx = blockIdx.x, by = blockIdx.y;
  const int wid = tid >> 6, lane = tid & 63;
  const int lr = lane & 15, lg = lane >> 4;
  const int wr = wid >> 1, wc = wid & 1;
  const int srow = tid >> 3, skg = tid & 7;

  const unsigned short* xhp = xh + (size_t)(by * 128 + srow) * 512 + skg * 8;
  const unsigned short* xlp = xl + (size_t)(by * 128 + srow) * 512 + skg * 8;
  const unsigned short* whp = wh + (size_t)(bx * 128 + srow) * 512 + skg * 8;
  const unsigned short* wlp = wl + (size_t)(bx * 128 + srow) * 512 + skg * 8;

  u16x8 rxh[4], rxl[4], rwh[4], rwl[4];
  auto loadk = [&](int k0) {
#pragma unroll
    for (int it = 0; it < 4; ++it) {
      const size_t o = (size_t)(32 * it) * 512 + k0;
      rxh[it] = *(const u16x8*)(xhp + o);
      rxl[it] = *(const u16x8*)(xlp + o);
      rwh[it] = *(const u16x8*)(whp + o);
      rwl[it] = *(const u16x8*)(wlp + o);
    }
  };

  f32x4 acc[4][4];
#pragma unroll
  for (int nt = 0; nt < 4; ++nt)
#pragma unroll
    for (int mt = 0; mt < 4; ++mt) acc[nt][mt] = (f32x4){0.f, 0.f, 0.f, 0.f};

  loadk(0);
  for (int s = 0; s < 8; ++s) {
    if (s) __syncthreads();
#pragma unroll
    for (int it = 0; it < 4; ++it) {
      const int base = (srow + 32 * it) * LSTR + skg * 8;
      *(u16x8*)&Xt[0][base] = rxh[it];
      *(u16x8*)&Xt[1][base] = rxl[it];
      *(u16x8*)&Wt[0][base] = rwh[it];
      *(u16x8*)&Wt[1][base] = rwl[it];
    }
    __syncthreads();
    if (s < 7) loadk((s + 1) * 64);
#pragma unroll
    for (int kh = 0; kh < 2; ++kh) {
      const int kbase = kh * 32 + lg * 8;
      bf16x8 Ah[4], Al[4], Bh[4], Bl[4];
#pragma unroll
      for (int nt = 0; nt < 4; ++nt) {
        const int n = wr * 64 + nt * 16 + lr;
        Ah[nt] = *(bf16x8*)&Wt[0][n * LSTR + kbase];
        Al[nt] = *(bf16x8*)&Wt[1][n * LSTR + kbase];
      }
#pragma unroll
      for (int mt = 0; mt < 4; ++mt) {
        const int m = wc * 64 + mt * 16 + lr;
        Bh[mt] = *(bf16x8*)&Xt[0][m * LSTR + kbase];
        Bl[mt] = *(bf16x8*)&Xt[1][m * LSTR + kbase];
      }
#pragma unroll
      for (int nt = 0; nt < 4; ++nt)
#pragma unroll
        for (int mt = 0; mt < 4; ++mt) {
          acc[nt][mt] = __builtin_amdgcn_mfma_f32_16x16x32_bf16(Ah[nt], Bh[mt], acc[nt][mt], 0, 0, 0);
          acc[nt][mt] = __builtin_amdgcn_mfma_f32_16x16x32_bf16(Ah[nt], Bl[mt], acc[nt][mt], 0, 0, 0);
          acc[nt][mt] = __builtin_amdgcn_mfma_f32_16x16x32_bf16(Al[nt], Bh[mt], acc[nt][mt], 0, 0, 0);
        }
    }
  }

  // epilogue: D col = m (x-row), D reg j -> n+j (w-col). float4 per acc.
#pragma unroll
  for (int mt = 0; mt < 4; ++mt) {
    const int m = by * 128 + wc * 64 + mt * 16 + lr;
    const int jj = m % 17;
    const int bt = m / 17;
    const int t = bt & 255;
    const int b = bt >> 8;
#pragma unroll
    for (int nt = 0; nt < 4; ++nt) {
      const int c = bx * 128 + wr * 64 + nt * 16 + lg * 4;
      const int qi = c >> 9;
      const int h = (c >> 6) & 7;
      const int dd = c & 63;
      float* dst = (qi == 0) ? q : (qi == 1) ? k : v;
      *(float4*)&dst[((size_t)((b * 8 + h) * 17 + jj)) * 16384 + t * 64 + dd] =
          make_float4(acc[nt][mt][0], acc[nt][mt][1], acc[nt][mt][2], acc[nt][mt][3]);
    }
  }
}

// ---------------- K2: split-precision MFMA DFT + af GEMM + freq softmax ----------------
__global__ __launch_bounds__(256) void freq_kernel(
    const float* __restrict__ qg, const float* __restrict__ kg,
    float* __restrict__ af_out) {
  __shared__ __attribute__((aligned(16))) unsigned short qT[2][64 * 256];
  __shared__ __attribute__((aligned(16))) unsigned short QF[4][64 * 64];
  __shared__ __attribute__((aligned(16))) unsigned short KF[4][64 * 64];

  const int tid = threadIdx.x;
  const int head = blockIdx.x;
  const int w = tid >> 6, lane = tid & 63;
  const int lr = lane & 15, lg = lane >> 4;
  const int f0 = w << 4;

  bf16x8 Ech[8], Ecl[8], Esh[8], Esl[8];
  {
    const int f = f0 + lr;
#pragma unroll
    for (int kb = 0; kb < 8; ++kb) {
      bf16x8 ch, cl, sh, sl;
#pragma unroll
      for (int i = 0; i < 8; ++i) {
        int t = kb * 32 + lg * 8 + i;
        int idx = (f * t) & 255;
        float s, c;
        __sincosf((float)idx * 0.02454369260617026f, &s, &c);
        unsigned short chh = f2bf(c);
        unsigned short shh = f2bf(s);
        ch[i] = (short)chh;
        cl[i] = (short)f2bf(c - bf2f(chh));
        sh[i] = (short)shh;
        sl[i] = (short)f2bf(s - bf2f(shh));
      }
      Ech[kb] = ch; Ecl[kb] = cl; Esh[kb] = sh; Esl[kb] = sl;
    }
  }

  for (int pass = 0; pass < 2; ++pass) {
    const float* src = pass ? kg : qg;
    __syncthreads();
    const float4* s4 = (const float4*)(src + head * 16384);
    for (int i = tid; i < 4096; i += 256) {
      int t = i >> 4, dq = i & 15;
      float4 v4 = s4[i];
      float vv[4] = {v4.x, v4.y, v4.z, v4.w};
#pragma unroll
      for (int c = 0; c < 4; ++c) {
        int d = dq * 4 + c;
        unsigned short hi = f2bf(vv[c]);
        unsigned short lo = f2bf(vv[c] - bf2f(hi));
        int byo = d * 512 + ((t * 2) ^ ((d & 31) << 4));
        *(unsigned short*)((char*)qT[0] + byo) = hi;
        *(unsigned short*)((char*)qT[1] + byo) = lo;
      }
    }
    __syncthreads();

    f32x4 ar[4], ai[4];
#pragma unroll
    for (int nt = 0; nt < 4; ++nt) {
      ar[nt] = (f32x4){0.f, 0.f, 0.f, 0.f};
      ai[nt] = (f32x4){0.f, 0.f, 0.f, 0.f};
    }
#pragma unroll
    for (int kb = 0; kb < 8; ++kb) {
#pragma unroll
      for (int nt = 0; nt < 4; ++nt) {
        const int d = nt * 16 + lr;
        const int byo = d * 512 + ((kb * 64 + lg * 16) ^ ((d & 31) << 4));
        bf16x8 bh = *(bf16x8*)((char*)qT[0] + byo);
        bf16x8 bl = *(bf16x8*)((char*)qT[1] + byo);
        ar[nt] = __builtin_amdgcn_mfma_f32_16x16x32_bf16(Ech[kb], bh, ar[nt], 0, 0, 0);
        ar[nt] = __builtin_amdgcn_mfma_f32_16x16x32_bf16(Ech[kb], bl, ar[nt], 0, 0, 0);
        ar[nt] = __builtin_amdgcn_mfma_f32_16x16x32_bf16(Ecl[kb], bh, ar[nt], 0, 0, 0);
        ai[nt] = __builtin_amdgcn_mfma_f32_16x16x32_bf16(Esh[kb], bh, ai[nt], 0, 0, 0);
        ai[nt] = __builtin_amdgcn_mfma_f32_16x16x32_bf16(Esh[kb], bl, ai[nt], 0, 0, 0);
        ai[nt] = __builtin_amdgcn_mfma_f32_16x16x32_bf16(Esl[kb], bh, ai[nt], 0, 0, 0);
      }
    }
    unsigned short(*DST)[64 * 64] = pass ? KF : QF;
#pragma unroll
    for (int nt = 0; nt < 4; ++nt) {
#pragma unroll
      for (int j = 0; j < 4; ++j) {
        const int f = f0 + lg * 4 + j;
        const int d = nt * 16 + lr;
        const int byo = f * 128 + ((d * 2) ^ ((f & 7) << 4));
        float vr = ar[nt][j], vi = ai[nt][j];
        unsigned short rh = f2bf(vr);
        unsigned short ih = f2bf(vi);
        *(unsigned short*)((char*)DST[0] + byo) = rh;
        *(unsigned short*)((char*)DST[1] + byo) = f2bf(vr - bf2f(rh));
        *(unsigned short*)((char*)DST[2] + byo) = ih;
        *(unsigned short*)((char*)DST[3] + byo) = f2bf(vi - bf2f(ih));
      }
    }
  }
  __syncthreads();

  f32x4 acc[4];
#pragma unroll
  for (int nt = 0; nt < 4; ++nt) acc[nt] = (f32x4){0.f, 0.f, 0.f, 0.f};
#pragma unroll
  for (int kb = 0; kb < 2; ++kb) {
    const int fA = f0 + lr;
    const int abyo = fA * 128 + ((kb * 64 + lg * 16) ^ ((fA & 7) << 4));
    bf16x8 arh = *(bf16x8*)((char*)QF[0] + abyo);
    bf16x8 arl = *(bf16x8*)((char*)QF[1] + abyo);
    bf16x8 aih = *(bf16x8*)((char*)QF[2] + abyo);
    bf16x8 ail = *(bf16x8*)((char*)QF[3] + abyo);
#pragma unroll
    for (int nt = 0; nt < 4; ++nt) {
      const int g = nt * 16 + lr;
      const int bbyo = g * 128 + ((kb * 64 + lg * 16) ^ ((g & 7) << 4));
      bf16x8 brh = *(bf16x8*)((char*)KF[0] + bbyo);
      bf16x8 brl = *(bf16x8*)((char*)KF[1] + bbyo);
      bf16x8 bih = *(bf16x8*)((char*)KF[2] + bbyo);
      bf16x8 bil = *(bf16x8*)((char*)KF[3] + bbyo);
      acc[nt] = __builtin_amdgcn_mfma_f32_16x16x32_bf16(arh, brh, acc[nt], 0, 0, 0);
      acc[nt] = __builtin_amdgcn_mfma_f32_16x16x32_bf16(arh, brl, acc[nt], 0, 0, 0);
      acc[nt] = __builtin_amdgcn_mfma_f32_16x16x32_bf16(arl, brh, acc[nt], 0, 0, 0);
      acc[nt] = __builtin_amdgcn_mfma_f32_16x16x32_bf16(aih, bih, acc[nt], 0, 0, 0);
      acc[nt] = __builtin_amdgcn_mfma_f32_16x16x32_bf16(aih, bil, acc[nt], 0, 0, 0);
      acc[nt] = __builtin_amdgcn_mfma_f32_16x16x32_bf16(ail, bih, acc[nt], 0, 0, 0);
    }
  }

  float* outh = af_out + head * 4096;
#pragma unroll
  for (int j = 0; j < 4; ++j) {
    float m = fmaxf(fmaxf(acc[0][j], acc[1][j]), fmaxf(acc[2][j], acc[3][j]));
#pragma unroll
    for (int mask = 1; mask < 16; mask <<= 1) m = fmaxf(m, __shfl_xor(m, mask));
    float e[4];
    float rs = 0.f;
#pragma unroll
    for (int nt = 0; nt < 4; ++nt) {
      e[nt] = __expf((acc[nt][j] - m) * SCALE);
      rs += e[nt];
    }
#pragma unroll
    for (int mask = 1; mask < 16; mask <<= 1) rs += __shfl_xor(rs, mask);
    const float inv = 1.0f / rs;
    const int f = f0 + lg * 4 + j;
#pragma unroll
    for (int nt = 0; nt < 4; ++nt) outh[f * 64 + nt * 16 + lr] = e[nt] * inv;
  }
}

// ---------------- K3: MFMA attention (unchanged, verified) ----------------
__global__ __launch_bounds__(256) void attn_kernel(
    const float* __restrict__ qg, const float* __restrict__ kg,
    const float* __restrict__ vg, const float* __restrict__ af,
    const float* __restrict__ att_map, const float* __restrict__ weight,
    const float* __restrict__ fgate, float* __restrict__ out_perm) {
  __shared__ unsigned short Ks[256 * 64];
  __shared__ unsigned short Vt[64 * 256];
  __shared__ unsigned short afl[64 * 66];
  __shared__ unsigned short Psc[4][16 * 40];

  const int tid = threadIdx.x;
  const int t0 = blockIdx.x << 6;
  const int head = blockIdx.y;
  const int jj = head % 17;
  const int hb = head / 17;
  const int h = hb & 7;
  const int b = hb >> 3;

  const float4* ksrc = (const float4*)(kg + head * 16384);
  const float4* vsrc = (const float4*)(vg + head * 16384);
  for (int i = tid; i < 4096; i += 256) {
    int s = i >> 4, dq = i & 15;
    float4 kf = ksrc[i];
    ushort4 k4 = make_ushort4(f2bf(kf.x), f2bf(kf.y), f2bf(kf.z), f2bf(kf.w));
    int koff = s * 128 + ((dq * 8) ^ ((s & 7) << 4));
    *(ushort4*)((char*)Ks + koff) = k4;
    float4 vf = vsrc[i];
    float vv[4] = {vf.x, vf.y, vf.z, vf.w};
#pragma unroll
    for (int c = 0; c < 4; ++c) {
      int d = dq * 4 + c;
      int voff = d * 512 + ((s * 2) ^ ((d & 7) << 4));
      *(unsigned short*)((char*)Vt + voff) = f2bf(vv[c]);
    }
  }
  const float4* asrc = (const float4*)(af + head * 4096);
  for (int i = tid; i < 1024; i += 256) {
    float4 a4 = asrc[i];
    int f = i >> 4, gq = (i & 15) << 2;
    ushort4 a4b = make_ushort4(f2bf(a4.x), f2bf(a4.y), f2bf(a4.z), f2bf(a4.w));
    *(ushort4*)&afl[f * 66 + gq] = a4b;
  }
  __syncthreads();

  const int w = tid >> 6, lane = tid & 63;
  const int lr = lane & 15, lg = lane >> 4;
  const int tw = t0 + w * 16;

  bf16x8 aq[2];
  {
    const float* qrow = qg + head * 16384 + (tw + lr) * 64 + lg * 8;
#pragma unroll
    for (int kc = 0; kc < 2; ++kc) {
      float4 q0 = *(const float4*)(qrow + kc * 32);
      float4 q1 = *(const float4*)(qrow + kc * 32 + 4);
      bf16x8 a;
      a[0] = (short)f2bf(q0.x); a[1] = (short)f2bf(q0.y);
      a[2] = (short)f2bf(q0.z); a[3] = (short)f2bf(q0.w);
      a[4] = (short)f2bf(q1.x); a[5] = (short)f2bf(q1.y);
      a[6] = (short)f2bf(q1.z); a[7] = (short)f2bf(q1.w);
      aq[kc] = a;
    }
  }

  f32x4 S[16];
#pragma unroll
  for (int nt = 0; nt < 16; ++nt) {
    f32x4 accv = {0.f, 0.f, 0.f, 0.f};
#pragma unroll
    for (int kc = 0; kc < 2; ++kc) {
      int srow = nt * 16 + lr;
      int d0 = kc * 32 + lg * 8;
      int off = srow * 128 + ((d0 * 2) ^ ((srow & 7) << 4));
      bf16x8 bk = *(bf16x8*)((char*)Ks + off);
      accv = __builtin_amdgcn_mfma_f32_16x16x32_bf16(aq[kc], bk, accv, 0, 0, 0);
    }
    S[nt] = accv;
  }

  float inv[4], mrow[4];
#pragma unroll
  for (int j = 0; j < 4; ++j) {
    float m = -1e30f;
#pragma unroll
    for (int nt = 0; nt < 16; ++nt) m = fmaxf(m, S[nt][j]);
#pragma unroll
    for (int mask = 1; mask < 16; mask <<= 1) m = fmaxf(m, __shfl_xor(m, mask));
    mrow[j] = m;
  }
#pragma unroll
  for (int j = 0; j < 4; ++j) {
    float rs = 0.f;
#pragma unroll
    for (int nt = 0; nt < 16; ++nt) {
      float e = __expf((S[nt][j] - mrow[j]) * SCALE);
      S[nt][j] = e;
      rs += e;
    }
#pragma unroll
    for (int mask = 1; mask < 16; mask <<= 1) rs += __shfl_xor(rs, mask);
    inv[j] = 1.0f / rs;
  }

  {
    const float wv = weight[0];
    const float gate = 1.0f / (1.0f + __expf(-fgate[0]));
    const float* amh = att_map + (size_t)head * 65536;
#pragma unroll
    for (int j = 0; j < 4; ++j) {
      const int t = tw + lg * 4 + j;
      float srcf = fmaxf((t + 0.5f) * (129.0f / 256.0f) - 0.5f, 0.0f);
      int f0r = (int)srcf;
      float wf = srcf - (float)f0r;
      int f1r = f0r + 1;
      if (f1r > 128) f1r = 128;
      const bool v0 = (f0r < 64), v1 = (f1r < 64);
#pragma unroll
      for (int nt = 0; nt < 16; ++nt) {
        const int s = nt * 16 + lr;
        float am = amh[t * 256 + s];
        float srcg = fmaxf((s + 0.5f) * 0.25f - 0.5f, 0.0f);
        int g0 = (int)srcg;
        float wc = srcg - (float)g0;
        int g1 = g0 + 1;
        if (g1 > 63) g1 = 63;
        float fr = 0.f;
        if (v0)
          fr += (1.0f - wf) *
                (bf2f(afl[f0r * 66 + g0]) * (1.0f - wc) + bf2f(afl[f0r * 66 + g1]) * wc);
        if (v1)
          fr += wf *
                (bf2f(afl[f1r * 66 + g0]) * (1.0f - wc) + bf2f(afl[f1r * 66 + g1]) * wc);
        float pt = S[nt][j] * inv[j];
        S[nt][j] = wv * (gate * fr + (1.0f - gate) * pt) + (1.0f - wv) * am;
      }
    }
  }

  f32x4 O[4];
#pragma unroll
  for (int dt = 0; dt < 4; ++dt) O[dt] = (f32x4){0.f, 0.f, 0.f, 0.f};
  unsigned short* psc = Psc[w];
#pragma unroll
  for (int sb = 0; sb < 8; ++sb) {
#pragma unroll
    for (int half = 0; half < 2; ++half) {
      const int nt = sb * 2 + half;
#pragma unroll
      for (int j = 0; j < 4; ++j) {
        psc[(lg * 4 + j) * 40 + half * 16 + lr] = f2bf(S[nt][j]);
      }
    }
    bf16x8 pa = *(bf16x8*)&psc[lr * 40 + lg * 8];
#pragma unroll
    for (int dt = 0; dt < 4; ++dt) {
      int d = dt * 16 + lr;
      int s0 = sb * 32 + lg * 8;
      int off = d * 512 + ((s0 * 2) ^ ((d & 7) << 4));
      bf16x8 bv = *(bf16x8*)((char*)Vt + off);
      O[dt] = __builtin_amdgcn_mfma_f32_16x16x32_bf16(pa, bv, O[dt], 0, 0, 0);
    }
  }

#pragma unroll
  for (int j = 0; j < 4; ++j) {
    const int t = tw + lg * 4 + j;
    float* orow = out_perm + ((size_t)((b * 256 + t) * 17 + jj)) * 512 + h * 64;
#pragma unroll
    for (int dt = 0; dt < 4; ++dt) {
      orow[dt * 16 + lr] = O[dt][j];
    }
  }
}

// ---------------- K4: d_out = out_perm @ w_proj + b_proj (split-bf16 MFMA) --------
__global__ __launch_bounds__(256, 2) void proj_gemm(
    const float* __restrict__ A,
    const unsigned short* __restrict__ wh, const unsigned short* __restrict__ wl,
    const float* __restrict__ bias, float* __restrict__ out) {
  __shared__ __attribute__((aligned(16))) unsigned short Wt[2][128 * LSTR];
  __shared__ __attribute__((aligned(16))) unsigned short Xt[2][128 * LSTR];

  const int tid = threadIdx.x;
  const int bx = blockIdx.x, by = blockIdx.y;
  const int wid = tid >> 6, lane = tid & 63;
  const int lr = lane & 15, lg = lane >> 4;
  const int wr = wid >> 1, wc = wid & 1;
  const int srow = tid >> 3, skg = tid & 7;

  const float* ap = A + (size_t)(by * 128 + srow) * 512 + skg * 8;
  const unsigned short* whp = wh + (size_t)(bx * 128 + srow) * 512 + skg * 8;
  const unsigned short* wlp = wl + (size_t)(bx * 128 + srow) * 512 + skg * 8;

  float4 rA[4][2];
  u16x8 rwh[4], rwl[4];
  auto loadk = [&](int k0) {
#pragma unroll
    for (int it = 0; it < 4; ++it) {
      const size_t o = (size_t)(32 * it) * 512 + k0;
      rA[it][0] = *(const float4*)(ap + o);
      rA[it][1] = *(const float4*)(ap + o + 4);
      rwh[it] = *(const u16x8*)(whp + o);
      rwl[it] = *(const u16x8*)(wlp + o);
    }
  };

  f32x4 acc[4][4];
#pragma unroll
  for (int nt = 0; nt < 4; ++nt)
#pragma unroll
    for (int mt = 0; mt < 4; ++mt) acc[nt][mt] = (f32x4){0.f, 0.f, 0.f, 0.f};

  loadk(0);
  for (int s = 0; s < 8; ++s) {
    if (s) __syncthreads();
#pragma unroll
    for (int it = 0; it < 4; ++it) {
      const int base = (srow + 32 * it) * LSTR + skg * 8;
      float vv[8] = {rA[it][0].x, rA[it][0].y, rA[it][0].z, rA[it][0].w,
                     rA[it][1].x, rA[it][1].y, rA[it][1].z, rA[it][1].w};
      u16x8 hi, lo;
#pragma unroll
      for (int e = 0; e < 8; ++e) {
        unsigned short h = f2bf(vv[e]);
        hi[e] = h;
        lo[e] = f2bf(vv[e] - bf2f(h));
      }
      *(u16x8*)&Xt[0][base] = hi;
      *(u16x8*)&Xt[1][base] = lo;
      *(u16x8*)&Wt[0][base] = rwh[it];
      *(u16x8*)&Wt[1][base] = rwl[it];
    }
    __syncthreads();
    if (s < 7) loadk((s + 1) * 64);
#pragma unroll
    for (int kh = 0; kh < 2; ++kh) {
      const int kbase = kh * 32 + lg * 8;
      bf16x8 Ah[4], Al[4], Bh[4], Bl[4];
#pragma unroll
      for (int nt = 0; nt < 4; ++nt) {
        const int n = wr * 64 + nt * 16 + lr;
        Ah[nt] = *(bf16x8*)&Wt[0][n * LSTR + kbase];
        Al[nt] = *(bf16x8*)&Wt[1][n * LSTR + kbase];
      }
#pragma unroll
      for (int mt = 0; mt < 4; ++mt) {
        const int m = wc * 64 + mt * 16 + lr;
        Bh[mt] = *(bf16x8*)&Xt[0][m * LSTR + kbase];
        Bl[mt] = *(bf16x8*)&Xt[1][m * LSTR + kbase];
      }
#pragma unroll
      for (int nt = 0; nt < 4; ++nt)
#pragma unroll
        for (int mt = 0; mt < 4; ++mt) {
          acc[nt][mt] = __builtin_amdgcn_mfma_f32_16x16x32_bf16(Ah[nt], Bh[mt], acc[nt][mt], 0, 0, 0);
          acc[nt][mt] = __builtin_amdgcn_mfma_f32_16x16x32_bf16(Ah[nt], Bl[mt], acc[nt][mt], 0, 0, 0);
          acc[nt][mt] = __builtin_amdgcn_mfma_f32_16x16x32_bf16(Al[nt], Bh[mt], acc[nt][mt], 0, 0, 0);
        }
    }
  }

#pragma unroll
  for (int mt = 0; mt < 4; ++mt) {
    const int m = by * 128 + wc * 64 + mt * 16 + lr;
#pragma unroll
    for (int nt = 0; nt < 4; ++nt) {
      const int n = bx * 128 + wr * 64 + nt * 16 + lg * 4;
      float4 bi = *(const float4*)&bias[n];
      *(float4*)&out[(size_t)m * 512 + n] =
          make_float4(acc[nt][mt][0] + bi.x, acc[nt][mt][1] + bi.y,
                      acc[nt][mt][2] + bi.z, acc[nt][mt][3] + bi.w);
    }
  }
}

extern "C" void kernel_launch(void* const* d_in, const int* in_sizes, int n_in,
                              void* d_out, int out_size, void* d_ws, size_t ws_size,
                              hipStream_t stream) {
  (void)in_sizes; (void)n_in; (void)out_size; (void)ws_size;
  const float* x = (const float*)d_in[0];
  const float* att_map = (const float*)d_in[1];
  const float* weight = (const float*)d_in[2];
  const float* w_qkv = (const float*)d_in[3];
  const float* w_proj = (const float*)d_in[4];
  const float* b_proj = (const float*)d_in[5];
  const float* fgate = (const float*)d_in[6];
  float* out = (float*)d_out;

  char* ws = (char*)d_ws;
  const size_t HB = 35651584;   // 544*16384 f32 bytes
  const size_t AF = 8912896;    // af f32
  float* qb = (float*)(ws);
  float* kb = (float*)(ws + HB);
  float* vb = (float*)(ws + 2 * HB);
  float* af = (float*)(ws + 3 * HB);
  char* base = ws + 3 * HB + AF;
  // xh/xl alias out_perm (disjoint lifetimes: xhl dead after K1; out_perm born in K3)
  unsigned short* xh = (unsigned short*)(base);
  unsigned short* xl = (unsigned short*)(base + 17825792);
  float* out_perm = (float*)(base);
  unsigned short* wqh = (unsigned short*)(base + 35651584);
  unsigned short* wql = (unsigned short*)(base + 35651584 + 1572864);
  unsigned short* wph = (unsigned short*)(base + 35651584 + 2 * 1572864);
  unsigned short* wpl = (unsigned short*)(base + 35651584 + 2 * 1572864 + 524288);

  conv_x<<<4352, 256, 0, stream>>>(x, xh, xl);
  conv_wT<<<dim3(24, 8), 256, 0, stream>>>(w_qkv, wqh, wql, 1536);
  conv_wT<<<dim3(8, 8), 256, 0, stream>>>(w_proj, wph, wpl, 512);
  qkv_gemm<<<dim3(12, 136), 256, 0, stream>>>(xh, xl, wqh, wql, qb, kb, vb);
  freq_kernel<<<544, 256, 0, stream>>>(qb, kb, af);
  attn_kernel<<<dim3(4, 544), 256, 0, stream>>>(qb, kb, vb, af, att_map, weight,
                                                fgate, out_perm);
  proj_gemm<<<dim3(4, 136), 256, 0, stream>>>(out_perm, wph, wpl, b_proj, out);
}